// Round 2
// baseline (4933.938 us; speedup 1.0000x reference)
//
#include <hip/hip_runtime.h>

#define DIN 768
#define DL  12288
#define LSTRIDE 128

// ---------------- transpose: W_dec (DIN x DL) -> WT (DL x DIN) ----------------
__global__ __launch_bounds__(256) void k_transpose(const float* __restrict__ W,
                                                   float* __restrict__ WT)
{
  __shared__ float t[32][33];
  const int c0 = blockIdx.x * 32;
  const int r0 = blockIdx.y * 32;
  const int x = threadIdx.x;   // 0..31
  const int y = threadIdx.y;   // 0..7
#pragma unroll
  for (int dy = 0; dy < 32; dy += 8)
    t[y + dy][x] = W[(size_t)(r0 + y + dy) * DL + c0 + x];
  __syncthreads();
#pragma unroll
  for (int dy = 0; dy < 32; dy += 8)
    WT[(size_t)(c0 + y + dy) * DIN + r0 + x] = t[x][y + dy];
}

// ------------- encode: a = (x - b_pre) @ W_enc^T + b_enc, f64 accumulation -------------
#define EBM 128
#define EBN 128
#define EBK 16

__global__ __launch_bounds__(256) void k_encode(
    const float* __restrict__ x, const float* __restrict__ b_pre,
    const float* __restrict__ W, const float* __restrict__ b_enc,
    float* __restrict__ aout, int M, int N, int K)
{
  __shared__ float As[EBK][EBM + 4];
  __shared__ float Bs[EBK][EBN + 4];
  const int tid = threadIdx.x;
  const int tx = tid & 15;
  const int ty = tid >> 4;
  const int bm = blockIdx.y * EBM;
  const int bn = blockIdx.x * EBN;

  double acc[8][8];
#pragma unroll
  for (int i = 0; i < 8; ++i)
#pragma unroll
    for (int j = 0; j < 8; ++j) acc[i][j] = 0.0;

  const int lm = tid >> 2;          // 0..63
  const int lk = (tid & 3) << 2;    // 0,4,8,12

  for (int k0 = 0; k0 < K; k0 += EBK) {
#pragma unroll
    for (int rep = 0; rep < 2; ++rep) {
      const int m = lm + rep * 64;
      const float4 xv = *(const float4*)&x[(size_t)(bm + m) * K + k0 + lk];
      const float4 bp = *(const float4*)&b_pre[k0 + lk];
      As[lk + 0][m] = xv.x - bp.x;
      As[lk + 1][m] = xv.y - bp.y;
      As[lk + 2][m] = xv.z - bp.z;
      As[lk + 3][m] = xv.w - bp.w;
      const float4 wv = *(const float4*)&W[(size_t)(bn + m) * K + k0 + lk];
      Bs[lk + 0][m] = wv.x;
      Bs[lk + 1][m] = wv.y;
      Bs[lk + 2][m] = wv.z;
      Bs[lk + 3][m] = wv.w;
    }
    __syncthreads();
#pragma unroll 4
    for (int kk = 0; kk < EBK; ++kk) {
      const float4 a0 = *(const float4*)&As[kk][ty * 4];
      const float4 a1 = *(const float4*)&As[kk][64 + ty * 4];
      const float4 b0 = *(const float4*)&Bs[kk][tx * 4];
      const float4 b1 = *(const float4*)&Bs[kk][64 + tx * 4];
      const double av[8] = {a0.x, a0.y, a0.z, a0.w, a1.x, a1.y, a1.z, a1.w};
      const double bv[8] = {b0.x, b0.y, b0.z, b0.w, b1.x, b1.y, b1.z, b1.w};
#pragma unroll
      for (int i = 0; i < 8; ++i)
#pragma unroll
        for (int j = 0; j < 8; ++j)
          acc[i][j] = fma(av[i], bv[j], acc[i][j]);
    }
    __syncthreads();
  }

  const float4 be0 = *(const float4*)&b_enc[bn + tx * 4];
  const float4 be1 = *(const float4*)&b_enc[bn + 64 + tx * 4];
  const double be[8] = {be0.x, be0.y, be0.z, be0.w, be1.x, be1.y, be1.z, be1.w};
#pragma unroll
  for (int i = 0; i < 8; ++i) {
    const int m = bm + ((i < 4) ? (ty * 4 + i) : (64 + ty * 4 + (i - 4)));
    float4 o0, o1;
    o0.x = (float)(acc[i][0] + be[0]);
    o0.y = (float)(acc[i][1] + be[1]);
    o0.z = (float)(acc[i][2] + be[2]);
    o0.w = (float)(acc[i][3] + be[3]);
    o1.x = (float)(acc[i][4] + be[4]);
    o1.y = (float)(acc[i][5] + be[5]);
    o1.z = (float)(acc[i][6] + be[6]);
    o1.w = (float)(acc[i][7] + be[7]);
    *(float4*)&aout[(size_t)m * N + bn + tx * 4] = o0;
    *(float4*)&aout[(size_t)m * N + bn + 64 + tx * 4] = o1;
  }
}

// ------------- per-row top-k radix select (on positive-float bit patterns) -------------
// MODE 1: write compact (idx,val) lists.  MODE 2: write dense z row (zeros + scatter).
template <int MODE>
__global__ __launch_bounds__(256) void k_select(
    const float* __restrict__ a, const int* __restrict__ kp,
    float* __restrict__ z, int* __restrict__ lidx, float* __restrict__ lval)
{
  const int row = blockIdx.x;
  const int tid = threadIdx.x;
  const int k = min(kp[0], LSTRIDE);
  const float* ar = a + (size_t)row * DL;

  __shared__ float sv[DL];
  __shared__ unsigned hist[8][256];
  __shared__ unsigned totals[256];
  __shared__ unsigned s_prefix, s_need;
  __shared__ int s_cntG, s_cntE;
  __shared__ int eq[128];

  // load + relu (float4)
  for (int i = tid; i < DL / 4; i += 256) {
    float4 v = ((const float4*)ar)[i];
    v.x = fmaxf(v.x, 0.f);
    v.y = fmaxf(v.y, 0.f);
    v.z = fmaxf(v.z, 0.f);
    v.w = fmaxf(v.w, 0.f);
    ((float4*)sv)[i] = v;
  }
  if (tid == 0) { s_prefix = 0u; s_need = (unsigned)k; s_cntG = 0; s_cntE = 0; }
  __syncthreads();

  // 4 x 8-bit radix passes, MSB first; nonneg floats compare as uints
  for (int pass = 0; pass < 4; ++pass) {
    const int shift = 24 - 8 * pass;
    for (int i = tid; i < 8 * 256; i += 256) (&hist[0][0])[i] = 0u;
    __syncthreads();
    const unsigned pref = s_prefix;   // stable this pass (written only after last barrier)
    unsigned* h = hist[tid >> 5];
    for (int i = tid; i < DL; i += 256) {
      const unsigned u = __float_as_uint(sv[i]);
      if (pass == 0 || (u >> (shift + 8)) == pref)
        atomicAdd(&h[(u >> shift) & 255u], 1u);
    }
    __syncthreads();
    unsigned t = 0;
#pragma unroll
    for (int c = 0; c < 8; ++c) t += hist[c][tid];
    totals[tid] = t;
    __syncthreads();
    // --- race-free winner phase: snapshot need, compute predicate, barrier, write ---
    const unsigned need = s_need;     // every thread snapshots BEFORE anyone writes
    unsigned above = 0;
    for (int b = tid + 1; b < 256; ++b) above += totals[b];
    const bool win = (above < need) && (above + t >= need);  // unique under consistent need
    __syncthreads();                  // all snapshots complete before the single write
    if (win) {
      s_need = need - above;
      s_prefix = (pref << 8) | (unsigned)tid;
    }
    __syncthreads();
  }

  const unsigned T = s_prefix;      // bit pattern of k-th largest (post-relu)
  const unsigned need = s_need;     // how many ==T to include (>=1)

  for (int i = tid; i < DL; i += 256) {
    const unsigned u = __float_as_uint(sv[i]);
    if (u > T) {
      const int p = atomicAdd(&s_cntG, 1);
      if (MODE == 1 && p < LSTRIDE) {   // defensive clamp: never stomp other rows
        lidx[(size_t)row * LSTRIDE + p] = i;
        lval[(size_t)row * LSTRIDE + p] = sv[i];
      }
    } else if (u == T) {
      const int p = atomicAdd(&s_cntE, 1);
      if (p < 128) eq[p] = i;
    }
    if (MODE == 2) z[(size_t)row * DL + i] = (u > T) ? sv[i] : 0.f;
  }
  __syncthreads();

  if (tid == 0) {
    const int ne = min(s_cntE, 128);
    // ties broken by lowest index (jax.lax.top_k) -> sort ascending, take first `need`
    for (int i2 = 1; i2 < ne; ++i2) {
      const int v = eq[i2];
      int j2 = i2 - 1;
      while (j2 >= 0 && eq[j2] > v) { eq[j2 + 1] = eq[j2]; --j2; }
      eq[j2 + 1] = v;
    }
    const int nd = min((int)need, ne);
    const int nG = min(s_cntG, LSTRIDE);
    for (int j = 0; j < nd && nG + j < LSTRIDE; ++j) {
      if (MODE == 1) {
        lidx[(size_t)row * LSTRIDE + nG + j] = eq[j];
        lval[(size_t)row * LSTRIDE + nG + j] = __uint_as_float(T);
      } else {
        z[(size_t)row * DL + eq[j]] = __uint_as_float(T);
      }
    }
    if (MODE == 1) {  // degenerate-case padding so decode reads defined data
      for (int j = min(nG + nd, LSTRIDE); j < k; ++j) {
        lidx[(size_t)row * LSTRIDE + j] = 0;
        lval[(size_t)row * LSTRIDE + j] = 0.f;
      }
    }
  }
}

// ------------- sparse decode: x_hat[row,:] = sum_j val_j * WT[idx_j,:] + b_dec -------------
__global__ __launch_bounds__(256) void k_decode(
    const float* __restrict__ WT, const int* __restrict__ lidx,
    const float* __restrict__ lval, const int* __restrict__ kp,
    const float* __restrict__ b_dec, float* __restrict__ xhat)
{
  const int row = blockIdx.x;
  const int tid = threadIdx.x;
  const int k = min(kp[0], LSTRIDE);
  __shared__ int sidx[LSTRIDE];
  __shared__ float sval[LSTRIDE];
  if (tid < k) {
    int idx = lidx[(size_t)row * LSTRIDE + tid];
    sidx[tid] = min(max(idx, 0), DL - 1);   // defensive clamp
    sval[tid] = lval[(size_t)row * LSTRIDE + tid];
  }
  __syncthreads();
  float acc0 = 0.f, acc1 = 0.f, acc2 = 0.f;
  for (int j = 0; j < k; ++j) {
    const float v = sval[j];
    const float* wr = WT + (size_t)sidx[j] * DIN;
    acc0 = fmaf(v, wr[tid], acc0);
    acc1 = fmaf(v, wr[tid + 256], acc1);
    acc2 = fmaf(v, wr[tid + 512], acc2);
  }
  float* xr = xhat + (size_t)row * DIN;
  xr[tid]       = acc0 + b_dec[tid];
  xr[tid + 256] = acc1 + b_dec[tid + 256];
  xr[tid + 512] = acc2 + b_dec[tid + 512];
}

extern "C" void kernel_launch(void* const* d_in, const int* in_sizes, int n_in,
                              void* d_out, int out_size, void* d_ws, size_t ws_size,
                              hipStream_t stream)
{
  const float* x     = (const float*)d_in[0];
  const float* b_pre = (const float*)d_in[1];
  const float* W_enc = (const float*)d_in[2];
  const float* b_enc = (const float*)d_in[3];
  const float* W_dec = (const float*)d_in[4];
  const float* b_dec = (const float*)d_in[5];
  const int*   kp    = (const int*)d_in[6];
  const int M = in_sizes[0] / DIN;   // 8192 rows

  float* xhat = (float*)d_out;                     // M*DIN
  float* z    = xhat + (size_t)M * DIN;            // M*DL
  float* a    = z + (size_t)M * DL;                // M*DL

  // scratch carved out of the z region (z is finalized by the LAST kernel):
  float* WT   = z;                                           // DL*DIN floats
  int*   lidx = (int*)(z + (size_t)DL * DIN);                // M*LSTRIDE ints
  float* lval = (float*)(z + (size_t)DL * DIN + (size_t)M * LSTRIDE);

  // 1) W_dec^T into z-scratch
  k_transpose<<<dim3(DL / 32, DIN / 32), dim3(32, 8), 0, stream>>>(W_dec, WT);
  // 2) encode (f64-accurate) -> a (final output region)
  k_encode<<<dim3(DL / EBN, M / EBM), 256, 0, stream>>>(x, b_pre, W_enc, b_enc, a, M, DL, DIN);
  // 3) top-k -> compact lists (z-scratch)
  k_select<1><<<M, 256, 0, stream>>>(a, kp, nullptr, lidx, lval);
  // 4) sparse decode -> x_hat
  k_decode<<<M, 256, 0, stream>>>(WT, lidx, lval, kp, b_dec, xhat);
  // 5) re-select and write dense z (overwrites all scratch; z becomes final)
  k_select<2><<<M, 256, 0, stream>>>(a, kp, z, nullptr, nullptr);
}

// Round 3
// 1920.795 us; speedup vs baseline: 2.5687x; 2.5687x over previous
//
#include <hip/hip_runtime.h>
#include <hip/hip_bf16.h>

#define DIN 768
#define DL  12288
#define CAP 192
#define MARGIN 0.01f

typedef __attribute__((ext_vector_type(8))) short short8v;
typedef __attribute__((ext_vector_type(4))) float f32x4;

__device__ __forceinline__ void gl_lds16(const void* g, void* s) {
  __builtin_amdgcn_global_load_lds(
      (const __attribute__((address_space(1))) unsigned int*)g,
      (__attribute__((address_space(3))) unsigned int*)s, 16, 0, 0);
}

__device__ __forceinline__ void bf16_split(float v, ushort& hi, ushort& lo) {
  __hip_bfloat16 h = __float2bfloat16(v);
  float rem = v - __bfloat162float(h);
  __hip_bfloat16 l = __float2bfloat16(rem);
  hi = *(ushort*)&h;
  lo = *(ushort*)&l;
}

// ---------------- split x - b_pre into bf16 hi/lo ----------------
__global__ __launch_bounds__(256) void k_split_x(const float* __restrict__ x,
    const float* __restrict__ b_pre, ushort* __restrict__ Ah, ushort* __restrict__ Al)
{
  const int i4 = blockIdx.x * 256 + threadIdx.x;     // one float4 group
  const int col4 = (i4 % (DIN / 4)) * 4;
  const float4 xv = *(const float4*)&x[(size_t)i4 * 4];
  const float4 bp = *(const float4*)&b_pre[col4];
  ushort4 h, l;
  bf16_split(xv.x - bp.x, h.x, l.x);
  bf16_split(xv.y - bp.y, h.y, l.y);
  bf16_split(xv.z - bp.z, h.z, l.z);
  bf16_split(xv.w - bp.w, h.w, l.w);
  *(ushort4*)&Ah[(size_t)i4 * 4] = h;
  *(ushort4*)&Al[(size_t)i4 * 4] = l;
}

__global__ __launch_bounds__(256) void k_split_w(const float* __restrict__ W,
    ushort* __restrict__ Bh, ushort* __restrict__ Bl)
{
  const int i4 = blockIdx.x * 256 + threadIdx.x;
  const float4 wv = *(const float4*)&W[(size_t)i4 * 4];
  ushort4 h, l;
  bf16_split(wv.x, h.x, l.x);
  bf16_split(wv.y, h.y, l.y);
  bf16_split(wv.z, h.z, l.z);
  bf16_split(wv.w, h.w, l.w);
  *(ushort4*)&Bh[(size_t)i4 * 4] = h;
  *(ushort4*)&Bl[(size_t)i4 * 4] = l;
}

// ---------------- transpose: W_dec (DIN x DL) -> WT (DL x DIN) ----------------
__global__ __launch_bounds__(256) void k_transpose(const float* __restrict__ W,
                                                   float* __restrict__ WT)
{
  __shared__ float t[32][33];
  const int c0 = blockIdx.x * 32;
  const int r0 = blockIdx.y * 32;
  const int x = threadIdx.x;
  const int y = threadIdx.y;
#pragma unroll
  for (int dy = 0; dy < 32; dy += 8)
    t[y + dy][x] = W[(size_t)(r0 + y + dy) * DL + c0 + x];
  __syncthreads();
#pragma unroll
  for (int dy = 0; dy < 32; dy += 8)
    WT[(size_t)(c0 + y + dy) * DIN + r0 + x] = t[x][y + dy];
}

// ---------------- MFMA encode: a~ = (x-b_pre)@W_enc^T + b_enc (split-bf16, 3 products) -------
#define BM 128
#define BN 128
#define BK 32

__global__ __launch_bounds__(256) void k_encode_mfma(
    const ushort* __restrict__ Ah, const ushort* __restrict__ Al,
    const ushort* __restrict__ Bh, const ushort* __restrict__ Bl,
    const float* __restrict__ b_enc, float* __restrict__ aout)
{
  __shared__ ushort sAh[BM][BK], sAl[BM][BK], sBh[BN][BK], sBl[BN][BK];
  const int tid  = threadIdx.x;
  const int wave = tid >> 6;
  const int lane = tid & 63;

  // XCD-chunked swizzle: 6144 blocks; xcd gets a 12-wide bn panel; bn fastest for A-reuse
  const int xcd = blockIdx.x & 7;
  const int within = blockIdx.x >> 3;          // 0..767
  const int bm = (within / 12) * BM;
  const int bn = (xcd * 12 + (within % 12)) * BN;

  const int srow = wave * 32 + (lane >> 2);    // staging row (first half)
  const int scol = (lane & 3) * 8;             // staging col (bf16 elems)
  const ushort* gAh = Ah + (size_t)(bm + srow) * DIN + scol;
  const ushort* gAl = Al + (size_t)(bm + srow) * DIN + scol;
  const ushort* gBh = Bh + (size_t)(bn + srow) * DIN + scol;
  const ushort* gBl = Bl + (size_t)(bn + srow) * DIN + scol;

  f32x4 acc[4][4];
#pragma unroll
  for (int i = 0; i < 4; ++i)
#pragma unroll
    for (int j = 0; j < 4; ++j) acc[i][j] = f32x4{0.f, 0.f, 0.f, 0.f};

  const int fr = lane & 15;      // fragment row (m or n within 16)
  const int fc = lane >> 4;      // k-chunk 0..3
  const int wr = (wave >> 1) * 64;
  const int wc = (wave & 1) * 64;

  for (int k0 = 0; k0 < DIN; k0 += BK) {
    gl_lds16(gAh + k0,             &sAh[wave * 32][0]);
    gl_lds16(gAh + k0 + 16 * DIN,  &sAh[wave * 32 + 16][0]);
    gl_lds16(gAl + k0,             &sAl[wave * 32][0]);
    gl_lds16(gAl + k0 + 16 * DIN,  &sAl[wave * 32 + 16][0]);
    gl_lds16(gBh + k0,             &sBh[wave * 32][0]);
    gl_lds16(gBh + k0 + 16 * DIN,  &sBh[wave * 32 + 16][0]);
    gl_lds16(gBl + k0,             &sBl[wave * 32][0]);
    gl_lds16(gBl + k0 + 16 * DIN,  &sBl[wave * 32 + 16][0]);
    __syncthreads();   // compiler emits vmcnt(0) drain + barrier

    short8v afh[4], afl[4], bfh[4], bfl[4];
#pragma unroll
    for (int i = 0; i < 4; ++i) {
      afh[i] = *(const short8v*)&sAh[wr + i * 16 + fr][fc * 8];
      afl[i] = *(const short8v*)&sAl[wr + i * 16 + fr][fc * 8];
    }
#pragma unroll
    for (int j = 0; j < 4; ++j) {
      bfh[j] = *(const short8v*)&sBh[wc + j * 16 + fr][fc * 8];
      bfl[j] = *(const short8v*)&sBl[wc + j * 16 + fr][fc * 8];
    }
#pragma unroll
    for (int i = 0; i < 4; ++i)
#pragma unroll
      for (int j = 0; j < 4; ++j) {
        acc[i][j] = __builtin_amdgcn_mfma_f32_16x16x32_bf16(afh[i], bfh[j], acc[i][j], 0, 0, 0);
        acc[i][j] = __builtin_amdgcn_mfma_f32_16x16x32_bf16(afh[i], bfl[j], acc[i][j], 0, 0, 0);
        acc[i][j] = __builtin_amdgcn_mfma_f32_16x16x32_bf16(afl[i], bfh[j], acc[i][j], 0, 0, 0);
      }
    __syncthreads();
  }

#pragma unroll
  for (int j = 0; j < 4; ++j) {
    const int col = bn + wc + j * 16 + fr;
    const float be = b_enc[col];
#pragma unroll
    for (int i = 0; i < 4; ++i) {
      const int row0 = bm + wr + i * 16 + fc * 4;
#pragma unroll
      for (int r = 0; r < 4; ++r)
        aout[(size_t)(row0 + r) * DL + col] = acc[i][j][r] + be;
    }
  }
}

// ---------------- radix threshold + candidate band ----------------
__global__ __launch_bounds__(256) void k_select_cand(
    const float* __restrict__ a, const int* __restrict__ kp,
    int* __restrict__ candidx, int* __restrict__ ccnt)
{
  const int row = blockIdx.x;
  const int tid = threadIdx.x;
  const int k = min(max(kp[0], 1), 128);
  const float* ar = a + (size_t)row * DL;

  __shared__ float sv[DL];
  __shared__ unsigned hist[8][256];
  __shared__ unsigned totals[256];
  __shared__ unsigned s_prefix, s_need;
  __shared__ int s_cnt;

  for (int i = tid; i < DL / 4; i += 256) {
    float4 v = ((const float4*)ar)[i];
    v.x = fmaxf(v.x, 0.f); v.y = fmaxf(v.y, 0.f);
    v.z = fmaxf(v.z, 0.f); v.w = fmaxf(v.w, 0.f);
    ((float4*)sv)[i] = v;
  }
  if (tid == 0) { s_prefix = 0u; s_need = (unsigned)k; s_cnt = 0; }
  __syncthreads();

  for (int pass = 0; pass < 4; ++pass) {
    const int shift = 24 - 8 * pass;
    for (int i = tid; i < 8 * 256; i += 256) (&hist[0][0])[i] = 0u;
    __syncthreads();
    const unsigned pref = s_prefix;
    unsigned* h = hist[tid >> 5];
    for (int i = tid; i < DL; i += 256) {
      const unsigned u = __float_as_uint(sv[i]);
      if (pass == 0 || (u >> (shift + 8)) == pref)
        atomicAdd(&h[(u >> shift) & 255u], 1u);
    }
    __syncthreads();
    unsigned t = 0;
#pragma unroll
    for (int c = 0; c < 8; ++c) t += hist[c][tid];
    totals[tid] = t;
    __syncthreads();
    const unsigned need = s_need;            // snapshot BEFORE anyone writes
    unsigned above = 0;
    for (int b = tid + 1; b < 256; ++b) above += totals[b];
    const bool win = (above < need) && (above + t >= need);
    __syncthreads();                         // snapshots complete before the write
    if (win) { s_need = need - above; s_prefix = (pref << 8) | (unsigned)tid; }
    __syncthreads();
  }

  const float Tf = __uint_as_float(s_prefix);
  const float Tm = Tf - MARGIN;
  for (int i = tid; i < DL; i += 256) {
    const float v = sv[i];
    if (v > 0.f && v >= Tm) {
      const int p = atomicAdd(&s_cnt, 1);
      if (p < CAP) candidx[(size_t)row * CAP + p] = i;
    }
  }
  __syncthreads();
  if (tid == 0) ccnt[row] = min(s_cnt, CAP);
}

// ---------------- exact f64 recheck of candidates; emit lists + (T32,need); patch a -------
__global__ __launch_bounds__(256) void k_recheck(
    const float* __restrict__ x, const float* __restrict__ b_pre,
    const float* __restrict__ W, const float* __restrict__ b_enc,
    const int* __restrict__ kp, const int* __restrict__ candidx,
    const int* __restrict__ ccnt, float* __restrict__ a,
    int* __restrict__ lidx, float* __restrict__ lval,
    float* __restrict__ wT32, int* __restrict__ wNeed)
{
  const int row = blockIdx.x;
  const int tid = threadIdx.x;
  const int kk = min(max(kp[0], 1), 128);
  const int C = min(ccnt[row], CAP);

  __shared__ double x0[DIN];
  __shared__ int cidx[CAP];
  __shared__ double cval[CAP];
  __shared__ float sT32;
  __shared__ int gcount;

  for (int i = tid; i < DIN; i += 256)
    x0[i] = (double)x[(size_t)row * DIN + i] - (double)b_pre[i];
  for (int i = tid; i < C; i += 256)
    cidx[i] = candidx[(size_t)row * CAP + i];
  if (tid == 0) { sT32 = 1e30f; gcount = 0; }
  __syncthreads();

  const int wave = tid >> 6, lane = tid & 63;
  for (int c = wave; c < C; c += 4) {
    const int idx = cidx[c];
    const float* wrow = W + (size_t)idx * DIN;
    double s = 0.0;
    for (int kx = lane; kx < DIN; kx += 64)
      s = fma(x0[kx], (double)wrow[kx], s);
#pragma unroll
    for (int m = 32; m; m >>= 1) s += __shfl_xor(s, m);
    if (lane == 0) cval[c] = s + (double)b_enc[idx];
  }
  __syncthreads();

  double myrv = 0.0;
  if (tid < C) {
    const int myidx = cidx[tid];
    const double v = cval[tid];
    myrv = v > 0.0 ? v : 0.0;
    int r = 0;
    for (int j = 0; j < C; ++j) {
      const double rj = cval[j] > 0.0 ? cval[j] : 0.0;
      if (rj > myrv || (rj == myrv && cidx[j] < myidx)) ++r;
    }
    a[(size_t)row * DL + myidx] = (float)v;            // patch a exact
    if (r < kk) {
      lidx[(size_t)row * 128 + r] = myidx;
      lval[(size_t)row * 128 + r] = (float)myrv;
    }
    if (r == kk - 1) sT32 = (float)myrv;
  }
  for (int t2 = C + tid; t2 < kk; t2 += 256) {         // only if C < kk (degenerate)
    lidx[(size_t)row * 128 + t2] = 0;
    lval[(size_t)row * 128 + t2] = 0.f;
  }
  __syncthreads();
  if (tid < C && (float)myrv > sT32) atomicAdd(&gcount, 1);
  __syncthreads();
  if (tid == 0) { wT32[row] = sT32; wNeed[row] = kk - gcount; }
}

// ---------------- sparse decode ----------------
__global__ __launch_bounds__(256) void k_decode(
    const float* __restrict__ WT, const int* __restrict__ lidx,
    const float* __restrict__ lval, const int* __restrict__ kp,
    const float* __restrict__ b_dec, float* __restrict__ xhat)
{
  const int row = blockIdx.x;
  const int tid = threadIdx.x;
  const int k = min(max(kp[0], 1), 128);
  __shared__ int sidx[128];
  __shared__ float sval[128];
  if (tid < k) {
    int idx = lidx[(size_t)row * 128 + tid];
    sidx[tid] = min(max(idx, 0), DL - 1);
    sval[tid] = lval[(size_t)row * 128 + tid];
  }
  __syncthreads();
  float acc0 = 0.f, acc1 = 0.f, acc2 = 0.f;
  for (int j = 0; j < k; ++j) {
    const float v = sval[j];
    const float* wr = WT + (size_t)sidx[j] * DIN;
    acc0 = fmaf(v, wr[tid], acc0);
    acc1 = fmaf(v, wr[tid + 256], acc1);
    acc2 = fmaf(v, wr[tid + 512], acc2);
  }
  float* xr = xhat + (size_t)row * DIN;
  xr[tid]       = acc0 + b_dec[tid];
  xr[tid + 256] = acc1 + b_dec[tid + 256];
  xr[tid + 512] = acc2 + b_dec[tid + 512];
}

// ---------------- final dense z write ----------------
__global__ __launch_bounds__(256) void k_zfinal(
    const float* __restrict__ a, const float* __restrict__ wT32,
    const int* __restrict__ wNeed, float* __restrict__ z)
{
  const int row = blockIdx.x;
  const int tid = threadIdx.x;
  const float T = wT32[row];
  const int need0 = wNeed[row];
  __shared__ int eq[CAP];
  __shared__ int ecnt;
  if (tid == 0) ecnt = 0;
  __syncthreads();
  const float* ar = a + (size_t)row * DL;
  float* zr = z + (size_t)row * DL;
  for (int i = tid * 4; i < DL; i += 1024) {
    const float4 v = *(const float4*)&ar[i];
    float4 o;
    const float r0 = fmaxf(v.x, 0.f), r1 = fmaxf(v.y, 0.f);
    const float r2 = fmaxf(v.z, 0.f), r3 = fmaxf(v.w, 0.f);
    o.x = (r0 > T) ? r0 : 0.f;
    o.y = (r1 > T) ? r1 : 0.f;
    o.z = (r2 > T) ? r2 : 0.f;
    o.w = (r3 > T) ? r3 : 0.f;
    if (T > 0.f) {
      if (r0 == T) { int p = atomicAdd(&ecnt, 1); if (p < CAP) eq[p] = i; }
      if (r1 == T) { int p = atomicAdd(&ecnt, 1); if (p < CAP) eq[p] = i + 1; }
      if (r2 == T) { int p = atomicAdd(&ecnt, 1); if (p < CAP) eq[p] = i + 2; }
      if (r3 == T) { int p = atomicAdd(&ecnt, 1); if (p < CAP) eq[p] = i + 3; }
    }
    *(float4*)&zr[i] = o;
  }
  __syncthreads();
  if (tid == 0) {
    const int ne = min(ecnt, CAP);
    for (int i2 = 1; i2 < ne; ++i2) {       // ties by lowest index: sort asc
      const int v = eq[i2];
      int j2 = i2 - 1;
      while (j2 >= 0 && eq[j2] > v) { eq[j2 + 1] = eq[j2]; --j2; }
      eq[j2 + 1] = v;
    }
    const int nd = min(need0, ne);
    for (int j = 0; j < nd; ++j) zr[eq[j]] = T;
  }
}

extern "C" void kernel_launch(void* const* d_in, const int* in_sizes, int n_in,
                              void* d_out, int out_size, void* d_ws, size_t ws_size,
                              hipStream_t stream)
{
  const float* x     = (const float*)d_in[0];
  const float* b_pre = (const float*)d_in[1];
  const float* W_enc = (const float*)d_in[2];
  const float* b_enc = (const float*)d_in[3];
  const float* W_dec = (const float*)d_in[4];
  const float* b_dec = (const float*)d_in[5];
  const int*   kp    = (const int*)d_in[6];
  const int M = in_sizes[0] / DIN;   // 8192

  float* xhat = (float*)d_out;
  float* z    = xhat + (size_t)M * DIN;
  float* a    = z + (size_t)M * DL;

  // z-region scratch (z finalized by the LAST kernel; strict producer/consumer order):
  float* WT      = z;                                        // DL*DIN floats
  int*   candidx = (int*)(WT + (size_t)DL * DIN);            // M*CAP
  int*   lidx    = candidx + (size_t)M * CAP;                // M*128
  float* lval    = (float*)(lidx + (size_t)M * 128);         // M*128
  ushort* Ah = (ushort*)(lval + (size_t)M * 128);            // M*DIN
  ushort* Al = Ah + (size_t)M * DIN;
  ushort* Bh = Al + (size_t)M * DIN;                         // DL*DIN
  ushort* Bl = Bh + (size_t)DL * DIN;

  // tiny cross-kernel state in d_ws (96 KB): survives z-scratch overwrites
  float* wT32  = (float*)d_ws;
  int*   wNeed = (int*)d_ws + M;
  int*   wCcnt = (int*)d_ws + 2 * M;

  k_split_x<<<M * DIN / 1024, 256, 0, stream>>>(x, b_pre, Ah, Al);
  k_split_w<<<DL * DIN / 1024, 256, 0, stream>>>(W_enc, Bh, Bl);
  k_transpose<<<dim3(DL / 32, DIN / 32), dim3(32, 8), 0, stream>>>(W_dec, WT);
  k_encode_mfma<<<(M / BM) * (DL / BN), 256, 0, stream>>>(Ah, Al, Bh, Bl, b_enc, a);
  k_select_cand<<<M, 256, 0, stream>>>(a, kp, candidx, wCcnt);
  k_recheck<<<M, 256, 0, stream>>>(x, b_pre, W_enc, b_enc, kp, candidx, wCcnt,
                                   a, lidx, lval, wT32, wNeed);
  k_decode<<<M, 256, 0, stream>>>(WT, lidx, lval, kp, b_dec, xhat);
  k_zfinal<<<M, 256, 0, stream>>>(a, wT32, wNeed, z);
}

// Round 4
// 1085.809 us; speedup vs baseline: 4.5440x; 1.7690x over previous
//
#include <hip/hip_runtime.h>

#define DIN 768
#define DL  12288
#define CAP 320
#define MARGIN 0.02f
#define KMAX 128

typedef __attribute__((ext_vector_type(8))) _Float16 half8;
typedef __attribute__((ext_vector_type(4))) _Float16 half4v;
typedef __attribute__((ext_vector_type(4))) float f32x4;

__device__ __forceinline__ void gl_lds16(const void* g, void* s) {
  __builtin_amdgcn_global_load_lds(
      (const __attribute__((address_space(1))) unsigned int*)g,
      (__attribute__((address_space(3))) unsigned int*)s, 16, 0, 0);
}

// ---------------- fp16 conversions ----------------
__global__ __launch_bounds__(256) void k_split_x(const float* __restrict__ x,
    const float* __restrict__ b_pre, _Float16* __restrict__ Ah)
{
  const int i4 = blockIdx.x * 256 + threadIdx.x;
  const int col4 = (i4 % (DIN / 4)) * 4;
  const float4 xv = *(const float4*)&x[(size_t)i4 * 4];
  const float4 bp = *(const float4*)&b_pre[col4];
  half4v o;
  o.x = (_Float16)(xv.x - bp.x);
  o.y = (_Float16)(xv.y - bp.y);
  o.z = (_Float16)(xv.z - bp.z);
  o.w = (_Float16)(xv.w - bp.w);
  *(half4v*)&Ah[(size_t)i4 * 4] = o;
}

__global__ __launch_bounds__(256) void k_split_w(const float* __restrict__ W,
                                                 _Float16* __restrict__ Bh)
{
  const int i4 = blockIdx.x * 256 + threadIdx.x;
  const float4 wv = *(const float4*)&W[(size_t)i4 * 4];
  half4v o;
  o.x = (_Float16)wv.x; o.y = (_Float16)wv.y;
  o.z = (_Float16)wv.z; o.w = (_Float16)wv.w;
  *(half4v*)&Bh[(size_t)i4 * 4] = o;
}

// ---------------- transpose: W_dec (DIN x DL) f32 -> WT (DL x DIN) fp16 ----------------
__global__ __launch_bounds__(256) void k_transpose(const float* __restrict__ W,
                                                   _Float16* __restrict__ WT)
{
  __shared__ float t[32][33];
  const int c0 = blockIdx.x * 32;
  const int r0 = blockIdx.y * 32;
  const int x = threadIdx.x;
  const int y = threadIdx.y;
#pragma unroll
  for (int dy = 0; dy < 32; dy += 8)
    t[y + dy][x] = W[(size_t)(r0 + y + dy) * DL + c0 + x];
  __syncthreads();
#pragma unroll
  for (int dy = 0; dy < 32; dy += 8)
    WT[(size_t)(c0 + y + dy) * DIN + r0 + x] = (_Float16)t[x][y + dy];
}

// ---------------- fp16 MFMA encode (single product; BK=64; swizzled LDS; 2-phase) --------
#define BM 128
#define BN 128
#define BKE 64
#define KITER (DIN / BKE)   // 12

__global__ __launch_bounds__(256) void k_encode_f16(
    const _Float16* __restrict__ Ah, const _Float16* __restrict__ Bh,
    const float* __restrict__ b_enc, float* __restrict__ aout)
{
  __shared__ _Float16 sA[2][BM][BKE];   // XOR-swizzled: logical chunk cc at phys cc^(row&7)
  __shared__ _Float16 sB[2][BN][BKE];
  const int tid = threadIdx.x, wave = tid >> 6, lane = tid & 63;

  // bijective XCD-chunked swizzle over 6144 blocks (nwg % 8 == 0)
  const int nwg = (8192 / BM) * (DL / BN);
  const int q = nwg >> 3;
  const int wg = (blockIdx.x & 7) * q + (blockIdx.x >> 3);
  const int bm = (wg / (DL / BN)) * BM;
  const int bn = (wg % (DL / BN)) * BN;

  // staging: lane l -> row l>>3 (of 8), phys chunk l&7; source k-offset pre-inverse-swizzled
  const int srow = lane >> 3;
  const int slog = ((lane & 7) ^ srow) << 3;   // logical chunk halves offset
  const _Float16* gA = Ah + (size_t)(bm + wave * 32 + srow) * DIN + slog;
  const _Float16* gB = Bh + (size_t)(bn + wave * 32 + srow) * DIN + slog;

  f32x4 acc[4][4];
#pragma unroll
  for (int i = 0; i < 4; ++i)
#pragma unroll
    for (int j = 0; j < 4; ++j) acc[i][j] = f32x4{0.f, 0.f, 0.f, 0.f};

  const int fr = lane & 15, fc = lane >> 4;
  const int wr = (wave >> 1) * 64, wc = (wave & 1) * 64;

#define STAGE(buf, k0)                                                          \
  {                                                                             \
    _Pragma("unroll")                                                           \
    for (int c = 0; c < 4; ++c) {                                               \
      gl_lds16(gA + (size_t)c * 8 * DIN + (k0), &sA[buf][wave * 32 + c * 8][0]);\
      gl_lds16(gB + (size_t)c * 8 * DIN + (k0), &sB[buf][wave * 32 + c * 8][0]);\
    }                                                                           \
  }

  STAGE(0, 0)
  __syncthreads();
  for (int t = 0; t < KITER; ++t) {
    if (t + 1 < KITER) STAGE((t + 1) & 1, (t + 1) * BKE)   // prefetch next tile
    const char* baseA = (const char*)&sA[t & 1][0][0];
    const char* baseB = (const char*)&sB[t & 1][0][0];
#pragma unroll
    for (int kk = 0; kk < 2; ++kk) {
      half8 af[4], bf[4];
#pragma unroll
      for (int i = 0; i < 4; ++i) {
        const int row = wr + i * 16 + fr;
        const int phys = (kk * 4 + fc) ^ (fr & 7);
        af[i] = *(const half8*)(baseA + row * (BKE * 2) + phys * 16);
      }
#pragma unroll
      for (int j = 0; j < 4; ++j) {
        const int row = wc + j * 16 + fr;
        const int phys = (kk * 4 + fc) ^ (fr & 7);
        bf[j] = *(const half8*)(baseB + row * (BKE * 2) + phys * 16);
      }
#pragma unroll
      for (int i = 0; i < 4; ++i)
#pragma unroll
        for (int j = 0; j < 4; ++j)
          acc[i][j] = __builtin_amdgcn_mfma_f32_16x16x32_f16(af[i], bf[j], acc[i][j], 0, 0, 0);
    }
    __syncthreads();   // drains prefetch (vmcnt) + protects buffer reuse
  }

#pragma unroll
  for (int j = 0; j < 4; ++j) {
    const int col = bn + wc + j * 16 + fr;
    const float be = b_enc[col];
#pragma unroll
    for (int i = 0; i < 4; ++i) {
      const int row0 = bm + wr + i * 16 + fc * 4;
#pragma unroll
      for (int r = 0; r < 4; ++r)
        aout[(size_t)(row0 + r) * DL + col] = acc[i][j][r] + be;
    }
  }
#undef STAGE
}

// ---------------- candidate select: register-resident, adaptive histogram ----------------
// WRITE_Z=1: also zero the dense z row (fused path). candidx stored in xhat slot.
template <int WRITE_Z>
__global__ __launch_bounds__(256) void k_select_cand(
    const float* __restrict__ a, const int* __restrict__ kp,
    float* __restrict__ z, float* __restrict__ xhat_slots, int* __restrict__ ccnt)
{
  const int row = blockIdx.x, tid = threadIdx.x;
  const unsigned k = (unsigned)min(max(kp[0], 1), KMAX);
  const float* ar = a + (size_t)row * DL;
  int* candidx = (int*)((char*)xhat_slots + (size_t)row * 3072 + 1024);

  __shared__ unsigned hist[4][512];
  __shared__ unsigned tot[512];
  __shared__ unsigned suf[256];
  __shared__ float s_wmax[4];
  __shared__ float s_Tm;
  __shared__ int s_cnt;

  float4 v[12];
#pragma unroll
  for (int j = 0; j < 12; ++j) {
    float4 t4 = ((const float4*)ar)[tid + 256 * j];
    t4.x = fmaxf(t4.x, 0.f); t4.y = fmaxf(t4.y, 0.f);
    t4.z = fmaxf(t4.z, 0.f); t4.w = fmaxf(t4.w, 0.f);
    v[j] = t4;
    if (WRITE_Z) {
      const float4 zz = {0.f, 0.f, 0.f, 0.f};
      ((float4*)(z + (size_t)row * DL))[tid + 256 * j] = zz;
    }
  }
  float m = 0.f;
#pragma unroll
  for (int j = 0; j < 12; ++j)
    m = fmaxf(m, fmaxf(fmaxf(v[j].x, v[j].y), fmaxf(v[j].z, v[j].w)));
#pragma unroll
  for (int off = 32; off; off >>= 1) m = fmaxf(m, __shfl_xor(m, off));
  if ((tid & 63) == 0) s_wmax[tid >> 6] = m;
  if (tid == 0) { s_cnt = 0; s_Tm = -1.f; }
  __syncthreads();
  const float rmax = fmaxf(fmaxf(s_wmax[0], s_wmax[1]), fmaxf(s_wmax[2], s_wmax[3]));

  float Tm;
  if (rmax <= 0.f) {
    Tm = 1e30f;   // no positives -> no candidates (degenerate path handled downstream)
  } else {
    const float scale = 512.f / rmax;
    unsigned need = k;
    bool found = false;
    for (int phase = 0; phase < 2 && !found; ++phase) {
      for (int i = tid; i < 4 * 512; i += 256) (&hist[0][0])[i] = 0u;
      __syncthreads();
      unsigned* h = hist[tid >> 6];
      const float sc = (phase == 0) ? scale : scale * 8.f;
#pragma unroll
      for (int j = 0; j < 12; ++j) {
        const float vv[4] = {v[j].x, v[j].y, v[j].z, v[j].w};
#pragma unroll
        for (int e = 0; e < 4; ++e) {
          const float val = vv[e];
          if (val > 0.f) {
            const float fb = val * scale;
            if (phase == 0) {
              if (fb >= 64.f) atomicAdd(&h[min(511, (int)fb)], 1u);
            } else {
              if (fb < 64.f) atomicAdd(&h[min(511, (int)(val * sc))], 1u);
            }
          }
        }
      }
      __syncthreads();
      for (int b = tid; b < 512; b += 256)
        tot[b] = hist[0][b] + hist[1][b] + hist[2][b] + hist[3][b];
      __syncthreads();
      const unsigned st = tot[2 * tid] + tot[2 * tid + 1];
      suf[tid] = st;
      __syncthreads();
      for (int off = 1; off < 256; off <<= 1) {   // Hillis-Steele inclusive suffix scan
        const unsigned add = (tid + off < 256) ? suf[tid + off] : 0u;
        __syncthreads();
        suf[tid] += add;
        __syncthreads();
      }
      const unsigned total = suf[0];              // uniform across block
      if (total >= need) {
        const unsigned excl = suf[tid] - st;      // count in pairs above this one
        if (suf[tid] >= need && excl < need) {    // unique crossing owner
          const unsigned hi = tot[2 * tid + 1];
          const int bin = (excl + hi >= need) ? (2 * tid + 1) : (2 * tid);
          s_Tm = (float)bin / sc - MARGIN;
        }
        found = true;
      } else {
        need -= total;
      }
      __syncthreads();
    }
    Tm = s_Tm;   // -1.f if fewer than k positives: every positive is a candidate
  }

#pragma unroll
  for (int j = 0; j < 12; ++j) {
    const float vv[4] = {v[j].x, v[j].y, v[j].z, v[j].w};
#pragma unroll
    for (int e = 0; e < 4; ++e) {
      if (vv[e] > 0.f && vv[e] >= Tm) {
        const int p = atomicAdd(&s_cnt, 1);
        if (p < CAP) candidx[p] = (tid + 256 * j) * 4 + e;
      }
    }
  }
  __syncthreads();
  if (tid == 0) ccnt[row] = min(s_cnt, CAP);
}

// ---------------- exact f64 recheck; lists into xhat slot; optional z scatter ----------------
__global__ __launch_bounds__(256) void k_recheck(
    const float* __restrict__ x, const float* __restrict__ b_pre,
    const float* __restrict__ W, const float* __restrict__ b_enc,
    const int* __restrict__ kp, float* __restrict__ xhat_slots,
    const int* __restrict__ ccnt, float* __restrict__ a,
    float* __restrict__ wT32, int* __restrict__ wNeed,
    float* __restrict__ z, int writeZ)
{
  const int row = blockIdx.x, tid = threadIdx.x;
  const int kk = min(max(kp[0], 1), KMAX);
  const int C = min(ccnt[row], CAP);
  int* slot = (int*)((char*)xhat_slots + (size_t)row * 3072);
  int* lidx = slot;
  float* lval = (float*)(slot + 128);
  const int* candidx = slot + 256;

  __shared__ double x0[DIN];
  __shared__ int cidx[CAP];
  __shared__ double cval[CAP];
  __shared__ float sT32;
  __shared__ int gcount;

  for (int i = tid; i < DIN; i += 256)
    x0[i] = (double)x[(size_t)row * DIN + i] - (double)b_pre[i];
  for (int i = tid; i < C; i += 256) cidx[i] = candidx[i];
  if (tid == 0) { sT32 = 1e30f; gcount = 0; }
  __syncthreads();

  const int wave = tid >> 6, lane = tid & 63;
  for (int c = wave; c < C; c += 4) {
    const int idx = cidx[c];
    const float* wrow = W + (size_t)idx * DIN;
    double s = 0.0;
    for (int kx = lane; kx < DIN; kx += 64)
      s = fma(x0[kx], (double)wrow[kx], s);
#pragma unroll
    for (int mm = 32; mm; mm >>= 1) s += __shfl_xor(s, mm);
    if (lane == 0) cval[c] = s + (double)b_enc[idx];
  }
  __syncthreads();

  double myrv = 0.0;
  if (tid < C) {
    const int myidx = cidx[tid];
    const double vv = cval[tid];
    myrv = vv > 0.0 ? vv : 0.0;
    int r = 0;
    for (int j = 0; j < C; ++j) {
      const double rj = cval[j] > 0.0 ? cval[j] : 0.0;
      if (rj > myrv || (rj == myrv && cidx[j] < myidx)) ++r;
    }
    a[(size_t)row * DL + myidx] = (float)vv;          // patch a exact
    if (r < kk) {
      lidx[r] = myidx;
      lval[r] = (float)myrv;
      if (writeZ) z[(size_t)row * DL + myidx] = (float)myrv;   // fused path scatter
    }
    if (r == kk - 1) sT32 = (float)myrv;
  }
  for (int t2 = C + tid; t2 < kk; t2 += 256) { lidx[t2] = -1; lval[t2] = 0.f; }
  __syncthreads();
  if (tid < C && (float)myrv > sT32) atomicAdd(&gcount, 1);
  __syncthreads();
  if (tid == 0) { wT32[row] = sT32; wNeed[row] = kk - gcount; }
}

// ---------------- sparse decode (fp16 WT; list read from own xhat slot) ----------------
__global__ __launch_bounds__(256) void k_decode(
    const _Float16* __restrict__ WT, const int* __restrict__ kp,
    const float* __restrict__ b_dec, float* __restrict__ xhat)
{
  const int row = blockIdx.x, tid = threadIdx.x;
  const int k = min(max(kp[0], 1), KMAX);
  const int* slot = (const int*)((const char*)xhat + (size_t)row * 3072);
  __shared__ int sidx[KMAX];
  __shared__ float sval[KMAX];
  if (tid < k) {
    const int idx = slot[tid];
    sidx[tid] = (idx < 0 || idx >= DL) ? 0 : idx;
    sval[tid] = (idx < 0) ? 0.f : ((const float*)(slot + 128))[tid];
  }
  __syncthreads();   // slot fully read before output overwrites it
  float acc0 = 0.f, acc1 = 0.f, acc2 = 0.f;
  for (int j = 0; j < k; ++j) {
    const float vv = sval[j];
    const _Float16* wr = WT + (size_t)sidx[j] * DIN;
    acc0 = fmaf(vv, (float)wr[tid], acc0);
    acc1 = fmaf(vv, (float)wr[tid + 256], acc1);
    acc2 = fmaf(vv, (float)wr[tid + 512], acc2);
  }
  float* xr = xhat + (size_t)row * DIN;
  xr[tid]       = acc0 + b_dec[tid];
  xr[tid + 256] = acc1 + b_dec[tid + 256];
  xr[tid + 512] = acc2 + b_dec[tid + 512];
}

// ---------------- legacy final dense z write (small-ws fallback) ----------------
__global__ __launch_bounds__(256) void k_zfinal(
    const float* __restrict__ a, const float* __restrict__ wT32,
    const int* __restrict__ wNeed, float* __restrict__ z)
{
  const int row = blockIdx.x, tid = threadIdx.x;
  const float T = wT32[row];
  const int need0 = wNeed[row];
  __shared__ int eq[CAP];
  __shared__ int ecnt;
  if (tid == 0) ecnt = 0;
  __syncthreads();
  const float* ar = a + (size_t)row * DL;
  float* zr = z + (size_t)row * DL;
  for (int i = tid * 4; i < DL; i += 1024) {
    const float4 vv = *(const float4*)&ar[i];
    const float r0 = fmaxf(vv.x, 0.f), r1 = fmaxf(vv.y, 0.f);
    const float r2 = fmaxf(vv.z, 0.f), r3 = fmaxf(vv.w, 0.f);
    float4 o;
    o.x = (r0 > T) ? r0 : 0.f;
    o.y = (r1 > T) ? r1 : 0.f;
    o.z = (r2 > T) ? r2 : 0.f;
    o.w = (r3 > T) ? r3 : 0.f;
    if (T > 0.f) {
      if (r0 == T) { int p = atomicAdd(&ecnt, 1); if (p < CAP) eq[p] = i; }
      if (r1 == T) { int p = atomicAdd(&ecnt, 1); if (p < CAP) eq[p] = i + 1; }
      if (r2 == T) { int p = atomicAdd(&ecnt, 1); if (p < CAP) eq[p] = i + 2; }
      if (r3 == T) { int p = atomicAdd(&ecnt, 1); if (p < CAP) eq[p] = i + 3; }
    }
    *(float4*)&zr[i] = o;
  }
  __syncthreads();
  if (tid == 0) {
    const int ne = min(ecnt, CAP);
    for (int i2 = 1; i2 < ne; ++i2) {
      const int vv = eq[i2];
      int j2 = i2 - 1;
      while (j2 >= 0 && eq[j2] > vv) { eq[j2 + 1] = eq[j2]; --j2; }
      eq[j2 + 1] = vv;
    }
    const int nd = min(need0, ne);
    for (int j = 0; j < nd; ++j) zr[eq[j]] = T;
  }
}

extern "C" void kernel_launch(void* const* d_in, const int* in_sizes, int n_in,
                              void* d_out, int out_size, void* d_ws, size_t ws_size,
                              hipStream_t stream)
{
  const float* x     = (const float*)d_in[0];
  const float* b_pre = (const float*)d_in[1];
  const float* W_enc = (const float*)d_in[2];
  const float* b_enc = (const float*)d_in[3];
  const float* W_dec = (const float*)d_in[4];
  const float* b_dec = (const float*)d_in[5];
  const int*   kp    = (const int*)d_in[6];
  const int M = in_sizes[0] / DIN;   // 8192

  float* xhat = (float*)d_out;                  // M*DIN (slots: lists+candidx live here pre-decode)
  float* z    = xhat + (size_t)M * DIN;         // M*DL
  float* a    = z + (size_t)M * DL;             // M*DL

  // split buffers in z-region, PAST the legacy-WT span (first 9.44M halves);
  // consumed by encode before z is overwritten
  _Float16* Ah = (_Float16*)z + (size_t)12 * 1024 * 1024;   // 6.29M halves
  _Float16* Bh = (_Float16*)z + (size_t)20 * 1024 * 1024;   // 9.44M halves

  // tiny persistent state in d_ws
  float* wT32  = (float*)d_ws;
  int*   wNeed = (int*)d_ws + M;
  int*   wCcnt = (int*)d_ws + 2 * M;

  const size_t WT_off = 1u << 20;
  const size_t WT_bytes = (size_t)DL * DIN * 2;             // 18.9 MB
  const bool bigws = ws_size >= WT_off + WT_bytes;
  _Float16* WT = bigws ? (_Float16*)((char*)d_ws + WT_off)  // fused: WT survives z write
                       : (_Float16*)z;                      // legacy: WT at z base until zfinal

  k_split_x<<<M * DIN / 1024, 256, 0, stream>>>(x, b_pre, Ah);
  k_split_w<<<DL * DIN / 1024, 256, 0, stream>>>(W_enc, Bh);
  k_transpose<<<dim3(DL / 32, DIN / 32), dim3(32, 8), 0, stream>>>(W_dec, WT);
  k_encode_f16<<<(M / BM) * (DL / BN), 256, 0, stream>>>(Ah, Bh, b_enc, a);

  if (bigws) {
    k_select_cand<1><<<M, 256, 0, stream>>>(a, kp, z, xhat, wCcnt);   // + z bulk zero
    k_recheck<<<M, 256, 0, stream>>>(x, b_pre, W_enc, b_enc, kp, xhat, wCcnt,
                                     a, wT32, wNeed, z, 1);           // + z top-k scatter
    k_decode<<<M, 256, 0, stream>>>(WT, kp, b_dec, xhat);
  } else {
    k_select_cand<0><<<M, 256, 0, stream>>>(a, kp, z, xhat, wCcnt);
    k_recheck<<<M, 256, 0, stream>>>(x, b_pre, W_enc, b_enc, kp, xhat, wCcnt,
                                     a, wT32, wNeed, z, 0);
    k_decode<<<M, 256, 0, stream>>>(WT, kp, b_dec, xhat);   // reads WT from z base
    k_zfinal<<<M, 256, 0, stream>>>(a, wT32, wNeed, z);     // then overwrites z
  }
}

// Round 5
// 1067.720 us; speedup vs baseline: 4.6210x; 1.0169x over previous
//
#include <hip/hip_runtime.h>

#define DIN 768
#define DL  12288
#define CAP 320
#define MARGIN 0.02f
#define KMAX 128

typedef __attribute__((ext_vector_type(8))) _Float16 half8;
typedef __attribute__((ext_vector_type(4))) _Float16 half4v;
typedef __attribute__((ext_vector_type(4))) float f32x4;

__device__ __forceinline__ void gl_lds16(const void* g, void* s) {
  __builtin_amdgcn_global_load_lds(
      (const __attribute__((address_space(1))) unsigned int*)g,
      (__attribute__((address_space(3))) unsigned int*)s, 16, 0, 0);
}
__device__ __forceinline__ void wait_lgkm0_fence() {
  asm volatile("s_waitcnt lgkmcnt(0)" ::: "memory");
  __builtin_amdgcn_sched_barrier(0);   // rule #18: MFMA must not hoist past the wait
}
__device__ __forceinline__ void wait_vm0() {
  asm volatile("s_waitcnt vmcnt(0)" ::: "memory");
}

// ---------------- fp16 conversions ----------------
__global__ __launch_bounds__(256) void k_split_x(const float* __restrict__ x,
    const float* __restrict__ b_pre, _Float16* __restrict__ Ah)
{
  const int i4 = blockIdx.x * 256 + threadIdx.x;
  const int col4 = (i4 % (DIN / 4)) * 4;
  const float4 xv = *(const float4*)&x[(size_t)i4 * 4];
  const float4 bp = *(const float4*)&b_pre[col4];
  half4v o;
  o.x = (_Float16)(xv.x - bp.x);
  o.y = (_Float16)(xv.y - bp.y);
  o.z = (_Float16)(xv.z - bp.z);
  o.w = (_Float16)(xv.w - bp.w);
  *(half4v*)&Ah[(size_t)i4 * 4] = o;
}

__global__ __launch_bounds__(256) void k_split_w(const float* __restrict__ W,
                                                 _Float16* __restrict__ Bh)
{
  const int i4 = blockIdx.x * 256 + threadIdx.x;
  const float4 wv = *(const float4*)&W[(size_t)i4 * 4];
  half4v o;
  o.x = (_Float16)wv.x; o.y = (_Float16)wv.y;
  o.z = (_Float16)wv.z; o.w = (_Float16)wv.w;
  *(half4v*)&Bh[(size_t)i4 * 4] = o;
}

// ---------------- transpose: W_dec (DIN x DL) -> WT (DL x DIN) f32 ----------------
__global__ __launch_bounds__(256) void k_transpose(const float* __restrict__ W,
                                                   float* __restrict__ WT)
{
  __shared__ float t[32][33];
  const int c0 = blockIdx.x * 32;
  const int r0 = blockIdx.y * 32;
  const int x = threadIdx.x;
  const int y = threadIdx.y;
#pragma unroll
  for (int dy = 0; dy < 32; dy += 8)
    t[y + dy][x] = W[(size_t)(r0 + y + dy) * DL + c0 + x];
  __syncthreads();
#pragma unroll
  for (int dy = 0; dy < 32; dy += 8)
    WT[(size_t)(c0 + y + dy) * DIN + r0 + x] = t[x][y + dy];
}

// ------- fp16 MFMA encode: 256x256 tile, 8 waves, BK=64, phase-interleaved pipeline -------
#define BM 256
#define BN 256
#define BKE 64
#define NKT (DIN / BKE)   // 12 K-tiles

__global__ __launch_bounds__(512) void k_encode_f16(
    const _Float16* __restrict__ Ah, const _Float16* __restrict__ Bh,
    const float* __restrict__ b_enc, float* __restrict__ aout)
{
  __shared__ _Float16 sA[2][BM][BKE];   // 64 KB  (XOR-swizzled 16B chunks: phys = log ^ (row&7))
  __shared__ _Float16 sB[2][BN][BKE];   // 64 KB
  const int tid = threadIdx.x, wave = tid >> 6, lane = tid & 63;
  const int wm = wave >> 2, wn = wave & 3;          // 2 x 4 wave grid
  const int fr = lane & 15, fc = lane >> 4;

  // bijective XCD-chunked swizzle (nwg = 32*48 = 1536, %8 == 0)
  const int q = ((8192 / BM) * (DL / BN)) >> 3;
  const int wg = (blockIdx.x & 7) * q + (blockIdx.x >> 3);
  const int bm = (wg / (DL / BN)) * BM;
  const int bn = (wg % (DL / BN)) * BN;

  // staging: lane -> row (lane>>3) within 8-row segment, phys chunk lane&7;
  // global col pre-inverse-swizzled so linear LDS write yields swizzled layout
  const int lrow = lane >> 3;
  const int lcol = ((lane & 7) ^ lrow) << 3;
  const _Float16* gA = Ah + (size_t)(bm + lrow) * DIN + lcol;
  const _Float16* gB = Bh + (size_t)(bn + lrow) * DIN + lcol;

  f32x4 acc[8][4];
#pragma unroll
  for (int i = 0; i < 8; ++i)
#pragma unroll
    for (int j = 0; j < 4; ++j) acc[i][j] = f32x4{0.f, 0.f, 0.f, 0.f};

  // stage one whole K-tile (A 256x64 + B 256x64) into buffer `buf`; 8 gl_lds/thread,
  // wave w covers segments {w, w+8, w+16, w+24} (8 rows each)
#define STAGE_TILE(buf, tt)                                                      \
  {                                                                              \
    _Pragma("unroll")                                                            \
    for (int s4 = 0; s4 < 4; ++s4) {                                             \
      const int s8 = (wave + s4 * 8) * 8;                                        \
      gl_lds16(gA + (size_t)s8 * DIN + (tt) * BKE, &sA[buf][s8][0]);             \
      gl_lds16(gB + (size_t)s8 * DIN + (tt) * BKE, &sB[buf][s8][0]);             \
    }                                                                            \
  }

  // load the 12 b128 fragments for C-quadrant (mh, nh) of buffer p
#define LOADQ(p, mh, nh)                                                         \
  {                                                                              \
    const char* bA = (const char*)&sA[p][0][0];                                  \
    const char* bB = (const char*)&sB[p][0][0];                                  \
    _Pragma("unroll")                                                            \
    for (int i = 0; i < 4; ++i)                                                  \
      _Pragma("unroll")                                                          \
      for (int ks = 0; ks < 2; ++ks) {                                           \
        const int row = wm * 128 + ((mh) * 4 + i) * 16 + fr;                     \
        const int ph = (ks * 4 + fc) ^ (fr & 7);                                 \
        af[i][ks] = *(const half8*)(bA + row * (BKE * 2) + ph * 16);             \
      }                                                                          \
    _Pragma("unroll")                                                            \
    for (int j = 0; j < 2; ++j)                                                  \
      _Pragma("unroll")                                                          \
      for (int ks = 0; ks < 2; ++ks) {                                           \
        const int row = wn * 64 + ((nh) * 2 + j) * 16 + fr;                      \
        const int ph = (ks * 4 + fc) ^ (fr & 7);                                 \
        bf[j][ks] = *(const half8*)(bB + row * (BKE * 2) + ph * 16);             \
      }                                                                          \
  }

#define MFMAQ(mh, nh)                                                            \
  __builtin_amdgcn_s_setprio(1);                                                 \
  _Pragma("unroll")                                                              \
  for (int i = 0; i < 4; ++i)                                                    \
    _Pragma("unroll")                                                            \
    for (int j = 0; j < 2; ++j)                                                  \
      _Pragma("unroll")                                                          \
      for (int ks = 0; ks < 2; ++ks)                                             \
        acc[(mh) * 4 + i][(nh) * 2 + j] = __builtin_amdgcn_mfma_f32_16x16x32_f16( \
            af[i][ks], bf[j][ks], acc[(mh) * 4 + i][(nh) * 2 + j], 0, 0, 0);     \
  __builtin_amdgcn_s_setprio(0);

  half8 af[4][2], bf[2][2];

  STAGE_TILE(0, 0)
  wait_vm0();
  __builtin_amdgcn_s_barrier();

#pragma unroll 1
  for (int t = 0; t < NKT; ++t) {
    const int p = t & 1;
    // phase 0: Q(0,0) + issue next tile's stage early (3 phases of latency cover)
    LOADQ(p, 0, 0)
    if (t + 1 < NKT) STAGE_TILE(p ^ 1, t + 1)
    __builtin_amdgcn_s_barrier();
    wait_lgkm0_fence();
    MFMAQ(0, 0)
    __builtin_amdgcn_s_barrier();
    // phase 1: Q(0,1)
    LOADQ(p, 0, 1)
    __builtin_amdgcn_s_barrier();
    wait_lgkm0_fence();
    MFMAQ(0, 1)
    __builtin_amdgcn_s_barrier();
    // phase 2: Q(1,0)
    LOADQ(p, 1, 0)
    __builtin_amdgcn_s_barrier();
    wait_lgkm0_fence();
    MFMAQ(1, 0)
    __builtin_amdgcn_s_barrier();
    // phase 3: Q(1,1) + drain stages (2 barriers before next tile's ds_read)
    LOADQ(p, 1, 1)
    wait_vm0();
    __builtin_amdgcn_s_barrier();
    wait_lgkm0_fence();
    MFMAQ(1, 1)
    __builtin_amdgcn_s_barrier();
  }

#pragma unroll
  for (int j = 0; j < 4; ++j) {
    const int col = bn + wn * 64 + j * 16 + fr;
    const float be = b_enc[col];
#pragma unroll
    for (int i = 0; i < 8; ++i) {
      const int row0 = bm + wm * 128 + i * 16 + fc * 4;
#pragma unroll
      for (int r = 0; r < 4; ++r)
        aout[(size_t)(row0 + r) * DL + col] = acc[i][j][r] + be;
    }
  }
#undef STAGE_TILE
#undef LOADQ
#undef MFMAQ
}

// ---------------- candidate select: register-resident, adaptive histogram ----------------
template <int WRITE_Z>
__global__ __launch_bounds__(256) void k_select_cand(
    const float* __restrict__ a, const int* __restrict__ kp,
    float* __restrict__ z, float* __restrict__ xhat_slots, int* __restrict__ ccnt)
{
  const int row = blockIdx.x, tid = threadIdx.x;
  const unsigned k = (unsigned)min(max(kp[0], 1), KMAX);
  const float* ar = a + (size_t)row * DL;
  int* candidx = (int*)((char*)xhat_slots + (size_t)row * 3072 + 1024);

  __shared__ unsigned hist[4][512];
  __shared__ unsigned tot[512];
  __shared__ unsigned suf[256];
  __shared__ float s_wmax[4];
  __shared__ float s_Tm;
  __shared__ int s_cnt;

  float4 v[12];
#pragma unroll
  for (int j = 0; j < 12; ++j) {
    float4 t4 = ((const float4*)ar)[tid + 256 * j];
    t4.x = fmaxf(t4.x, 0.f); t4.y = fmaxf(t4.y, 0.f);
    t4.z = fmaxf(t4.z, 0.f); t4.w = fmaxf(t4.w, 0.f);
    v[j] = t4;
    if (WRITE_Z) {
      const float4 zz = {0.f, 0.f, 0.f, 0.f};
      ((float4*)(z + (size_t)row * DL))[tid + 256 * j] = zz;
    }
  }
  float m = 0.f;
#pragma unroll
  for (int j = 0; j < 12; ++j)
    m = fmaxf(m, fmaxf(fmaxf(v[j].x, v[j].y), fmaxf(v[j].z, v[j].w)));
#pragma unroll
  for (int off = 32; off; off >>= 1) m = fmaxf(m, __shfl_xor(m, off));
  if ((tid & 63) == 0) s_wmax[tid >> 6] = m;
  if (tid == 0) { s_cnt = 0; s_Tm = -1.f; }
  __syncthreads();
  const float rmax = fmaxf(fmaxf(s_wmax[0], s_wmax[1]), fmaxf(s_wmax[2], s_wmax[3]));

  float Tm;
  if (rmax <= 0.f) {
    Tm = 1e30f;
  } else {
    const float scale = 512.f / rmax;
    unsigned need = k;
    bool found = false;
    for (int phase = 0; phase < 2 && !found; ++phase) {
      for (int i = tid; i < 4 * 512; i += 256) (&hist[0][0])[i] = 0u;
      __syncthreads();
      unsigned* h = hist[tid >> 6];
      const float sc = (phase == 0) ? scale : scale * 8.f;
#pragma unroll
      for (int j = 0; j < 12; ++j) {
        const float vv[4] = {v[j].x, v[j].y, v[j].z, v[j].w};
#pragma unroll
        for (int e = 0; e < 4; ++e) {
          const float val = vv[e];
          if (val > 0.f) {
            const float fb = val * scale;
            if (phase == 0) {
              if (fb >= 64.f) atomicAdd(&h[min(511, (int)fb)], 1u);
            } else {
              if (fb < 64.f) atomicAdd(&h[min(511, (int)(val * sc))], 1u);
            }
          }
        }
      }
      __syncthreads();
      for (int b = tid; b < 512; b += 256)
        tot[b] = hist[0][b] + hist[1][b] + hist[2][b] + hist[3][b];
      __syncthreads();
      const unsigned st = tot[2 * tid] + tot[2 * tid + 1];
      suf[tid] = st;
      __syncthreads();
      for (int off = 1; off < 256; off <<= 1) {
        const unsigned add = (tid + off < 256) ? suf[tid + off] : 0u;
        __syncthreads();
        suf[tid] += add;
        __syncthreads();
      }
      const unsigned total = suf[0];
      if (total >= need) {
        const unsigned excl = suf[tid] - st;
        if (suf[tid] >= need && excl < need) {
          const unsigned hi = tot[2 * tid + 1];
          const int bin = (excl + hi >= need) ? (2 * tid + 1) : (2 * tid);
          s_Tm = (float)bin / sc - MARGIN;
        }
        found = true;
      } else {
        need -= total;
      }
      __syncthreads();
    }
    Tm = s_Tm;
  }

#pragma unroll
  for (int j = 0; j < 12; ++j) {
    const float vv[4] = {v[j].x, v[j].y, v[j].z, v[j].w};
#pragma unroll
    for (int e = 0; e < 4; ++e) {
      if (vv[e] > 0.f && vv[e] >= Tm) {
        const int p = atomicAdd(&s_cnt, 1);
        if (p < CAP) candidx[p] = (tid + 256 * j) * 4 + e;
      }
    }
  }
  __syncthreads();
  if (tid == 0) ccnt[row] = min(s_cnt, CAP);
}

// ---------------- exact f64 recheck; lists into xhat slot; optional z scatter ----------------
__global__ __launch_bounds__(256) void k_recheck(
    const float* __restrict__ x, const float* __restrict__ b_pre,
    const float* __restrict__ W, const float* __restrict__ b_enc,
    const int* __restrict__ kp, float* __restrict__ xhat_slots,
    const int* __restrict__ ccnt, float* __restrict__ a,
    float* __restrict__ wT32, int* __restrict__ wNeed,
    float* __restrict__ z, int writeZ)
{
  const int row = blockIdx.x, tid = threadIdx.x;
  const int kk = min(max(kp[0], 1), KMAX);
  const int C = min(ccnt[row], CAP);
  int* slot = (int*)((char*)xhat_slots + (size_t)row * 3072);
  int* lidx = slot;
  float* lval = (float*)(slot + 128);
  const int* candidx = slot + 256;

  __shared__ double x0[DIN];
  __shared__ int cidx[CAP];
  __shared__ double cval[CAP];
  __shared__ float sT32;
  __shared__ int gcount;

  for (int i = tid; i < DIN; i += 256)
    x0[i] = (double)x[(size_t)row * DIN + i] - (double)b_pre[i];
  for (int i = tid; i < C; i += 256) cidx[i] = candidx[i];
  if (tid == 0) { sT32 = 1e30f; gcount = 0; }
  __syncthreads();

  const int wave = tid >> 6, lane = tid & 63;
  for (int c = wave; c < C; c += 4) {
    const int idx = cidx[c];
    const float* wrow = W + (size_t)idx * DIN;
    double s = 0.0;
    for (int kx = lane; kx < DIN; kx += 64)
      s = fma(x0[kx], (double)wrow[kx], s);
#pragma unroll
    for (int mm = 32; mm; mm >>= 1) s += __shfl_xor(s, mm);
    if (lane == 0) cval[c] = s + (double)b_enc[idx];
  }
  __syncthreads();

  double myrv = 0.0;
  if (tid < C) {
    const int myidx = cidx[tid];
    const double vv = cval[tid];
    myrv = vv > 0.0 ? vv : 0.0;
    int r = 0;
    for (int j = 0; j < C; ++j) {
      const double rj = cval[j] > 0.0 ? cval[j] : 0.0;
      if (rj > myrv || (rj == myrv && cidx[j] < myidx)) ++r;
    }
    a[(size_t)row * DL + myidx] = (float)vv;
    if (r < kk) {
      lidx[r] = myidx;
      lval[r] = (float)myrv;
      if (writeZ) z[(size_t)row * DL + myidx] = (float)myrv;
    }
    if (r == kk - 1) sT32 = (float)myrv;
  }
  for (int t2 = C + tid; t2 < kk; t2 += 256) { lidx[t2] = -1; lval[t2] = 0.f; }
  __syncthreads();
  if (tid < C && (float)myrv > sT32) atomicAdd(&gcount, 1);
  __syncthreads();
  if (tid == 0) { wT32[row] = sT32; wNeed[row] = kk - gcount; }
}

// ---------------- sparse decode: f32 WT, float4 gathers (16B/lane) ----------------
__global__ __launch_bounds__(192) void k_decode(
    const float* __restrict__ WT, const int* __restrict__ kp,
    const float* __restrict__ b_dec, float* __restrict__ xhat)
{
  const int row = blockIdx.x, tid = threadIdx.x;
  const int k = min(max(kp[0], 1), KMAX);
  const int* slot = (const int*)((const char*)xhat + (size_t)row * 3072);
  __shared__ int sidx[KMAX];
  __shared__ float sval[KMAX];
  if (tid < k) {
    const int idx = slot[tid];
    sidx[tid] = (idx < 0 || idx >= DL) ? 0 : idx;
    sval[tid] = (idx < 0) ? 0.f : ((const float*)(slot + 128))[tid];
  }
  __syncthreads();   // slot fully read before xhat row is overwritten
  float4 acc = ((const float4*)b_dec)[tid];
  const float4* WT4 = (const float4*)WT;
  for (int j = 0; j < k; ++j) {
    const float vv = sval[j];
    const float4 w4 = WT4[(size_t)sidx[j] * (DIN / 4) + tid];
    acc.x = fmaf(vv, w4.x, acc.x);
    acc.y = fmaf(vv, w4.y, acc.y);
    acc.z = fmaf(vv, w4.z, acc.z);
    acc.w = fmaf(vv, w4.w, acc.w);
  }
  ((float4*)(xhat + (size_t)row * DIN))[tid] = acc;
}

// ---------------- legacy final dense z write (small-ws fallback) ----------------
__global__ __launch_bounds__(256) void k_zfinal(
    const float* __restrict__ a, const float* __restrict__ wT32,
    const int* __restrict__ wNeed, float* __restrict__ z)
{
  const int row = blockIdx.x, tid = threadIdx.x;
  const float T = wT32[row];
  const int need0 = wNeed[row];
  __shared__ int eq[CAP];
  __shared__ int ecnt;
  if (tid == 0) ecnt = 0;
  __syncthreads();
  const float* ar = a + (size_t)row * DL;
  float* zr = z + (size_t)row * DL;
  for (int i = tid * 4; i < DL; i += 1024) {
    const float4 vv = *(const float4*)&ar[i];
    const float r0 = fmaxf(vv.x, 0.f), r1 = fmaxf(vv.y, 0.f);
    const float r2 = fmaxf(vv.z, 0.f), r3 = fmaxf(vv.w, 0.f);
    float4 o;
    o.x = (r0 > T) ? r0 : 0.f;
    o.y = (r1 > T) ? r1 : 0.f;
    o.z = (r2 > T) ? r2 : 0.f;
    o.w = (r3 > T) ? r3 : 0.f;
    if (T > 0.f) {
      if (r0 == T) { int p = atomicAdd(&ecnt, 1); if (p < CAP) eq[p] = i; }
      if (r1 == T) { int p = atomicAdd(&ecnt, 1); if (p < CAP) eq[p] = i + 1; }
      if (r2 == T) { int p = atomicAdd(&ecnt, 1); if (p < CAP) eq[p] = i + 2; }
      if (r3 == T) { int p = atomicAdd(&ecnt, 1); if (p < CAP) eq[p] = i + 3; }
    }
    *(float4*)&zr[i] = o;
  }
  __syncthreads();
  if (tid == 0) {
    const int ne = min(ecnt, CAP);
    for (int i2 = 1; i2 < ne; ++i2) {
      const int vv = eq[i2];
      int j2 = i2 - 1;
      while (j2 >= 0 && eq[j2] > vv) { eq[j2 + 1] = eq[j2]; --j2; }
      eq[j2 + 1] = vv;
    }
    const int nd = min(need0, ne);
    for (int j = 0; j < nd; ++j) zr[eq[j]] = T;
  }
}

extern "C" void kernel_launch(void* const* d_in, const int* in_sizes, int n_in,
                              void* d_out, int out_size, void* d_ws, size_t ws_size,
                              hipStream_t stream)
{
  const float* x     = (const float*)d_in[0];
  const float* b_pre = (const float*)d_in[1];
  const float* W_enc = (const float*)d_in[2];
  const float* b_enc = (const float*)d_in[3];
  const float* W_dec = (const float*)d_in[4];
  const float* b_dec = (const float*)d_in[5];
  const int*   kp    = (const int*)d_in[6];
  const int M = in_sizes[0] / DIN;   // 8192

  float* xhat = (float*)d_out;                  // lists+candidx live in per-row slots here
  float* z    = xhat + (size_t)M * DIN;
  float* a    = z + (size_t)M * DL;

  // tiny persistent state at d_ws base
  float* wT32  = (float*)d_ws;
  int*   wNeed = (int*)d_ws + M;
  int*   wCcnt = (int*)d_ws + 2 * M;

  const bool bigws = ws_size >= ((size_t)192 << 20);
  float*    WT;
  _Float16 *Ah, *Bh;
  if (bigws) {   // all big scratch in d_ws; z-region untouched until select/recheck write it
    WT = (float*)((char*)d_ws + ((size_t)1 << 20));           // 37.7 MB
    Ah = (_Float16*)((char*)d_ws + ((size_t)64 << 20));       // 12.6 MB
    Bh = (_Float16*)((char*)d_ws + ((size_t)96 << 20));       // 18.9 MB
  } else {       // legacy: scratch in z-region with strict producer/consumer ordering
    WT = (float*)z;                                           // 9.44M floats
    Ah = (_Float16*)(z + (size_t)12 * 1024 * 1024);
    Bh = (_Float16*)(z + (size_t)20 * 1024 * 1024);
  }

  k_split_x<<<M * DIN / 1024, 256, 0, stream>>>(x, b_pre, Ah);
  k_split_w<<<DL * DIN / 1024, 256, 0, stream>>>(W_enc, Bh);
  k_transpose<<<dim3(DL / 32, DIN / 32), dim3(32, 8), 0, stream>>>(W_dec, WT);
  k_encode_f16<<<(M / BM) * (DL / BN), 512, 0, stream>>>(Ah, Bh, b_enc, a);

  if (bigws) {
    k_select_cand<1><<<M, 256, 0, stream>>>(a, kp, z, xhat, wCcnt);   // + z bulk zero
    k_recheck<<<M, 256, 0, stream>>>(x, b_pre, W_enc, b_enc, kp, xhat, wCcnt,
                                     a, wT32, wNeed, z, 1);           // + z top-k scatter
    k_decode<<<M, 192, 0, stream>>>(WT, kp, b_dec, xhat);
  } else {
    k_select_cand<0><<<M, 256, 0, stream>>>(a, kp, z, xhat, wCcnt);
    k_recheck<<<M, 256, 0, stream>>>(x, b_pre, W_enc, b_enc, kp, xhat, wCcnt,
                                     a, wT32, wNeed, z, 0);
    k_decode<<<M, 192, 0, stream>>>(WT, kp, b_dec, xhat);
    k_zfinal<<<M, 256, 0, stream>>>(a, wT32, wNeed, z);
  }
}

// Round 6
// 1000.478 us; speedup vs baseline: 4.9316x; 1.0672x over previous
//
#include <hip/hip_runtime.h>

#define DIN 768
#define DL  12288
#define CAP 320
#define MARGIN 0.02f
#define KMAX 128

typedef __attribute__((ext_vector_type(8))) _Float16 half8;
typedef __attribute__((ext_vector_type(4))) _Float16 half4v;
typedef __attribute__((ext_vector_type(4))) float f32x4;

__device__ __forceinline__ void gl_lds16(const void* g, void* s) {
  __builtin_amdgcn_global_load_lds(
      (const __attribute__((address_space(1))) unsigned int*)g,
      (__attribute__((address_space(3))) unsigned int*)s, 16, 0, 0);
}
__device__ __forceinline__ void wait_lgkm0_fence() {
  asm volatile("s_waitcnt lgkmcnt(0)" ::: "memory");
  __builtin_amdgcn_sched_barrier(0);   // rule #18
}
__device__ __forceinline__ void wait_vm0() {
  asm volatile("s_waitcnt vmcnt(0)" ::: "memory");
}

// ---------------- fp16 conversions ----------------
__global__ __launch_bounds__(256) void k_split_x(const float* __restrict__ x,
    const float* __restrict__ b_pre, _Float16* __restrict__ Ah)
{
  const int i4 = blockIdx.x * 256 + threadIdx.x;
  const int col4 = (i4 % (DIN / 4)) * 4;
  const float4 xv = *(const float4*)&x[(size_t)i4 * 4];
  const float4 bp = *(const float4*)&b_pre[col4];
  half4v o;
  o.x = (_Float16)(xv.x - bp.x);
  o.y = (_Float16)(xv.y - bp.y);
  o.z = (_Float16)(xv.z - bp.z);
  o.w = (_Float16)(xv.w - bp.w);
  *(half4v*)&Ah[(size_t)i4 * 4] = o;
}

__global__ __launch_bounds__(256) void k_split_w(const float* __restrict__ W,
                                                 _Float16* __restrict__ Bh)
{
  const int i4 = blockIdx.x * 256 + threadIdx.x;
  const float4 wv = *(const float4*)&W[(size_t)i4 * 4];
  half4v o;
  o.x = (_Float16)wv.x; o.y = (_Float16)wv.y;
  o.z = (_Float16)wv.z; o.w = (_Float16)wv.w;
  *(half4v*)&Bh[(size_t)i4 * 4] = o;
}

// ---------------- transpose: W_dec (DIN x DL) -> WT (DL x DIN), templated output ----------
template <typename OT>
__global__ __launch_bounds__(256) void k_transpose(const float* __restrict__ W,
                                                   OT* __restrict__ WT)
{
  __shared__ float t[32][33];
  const int c0 = blockIdx.x * 32;
  const int r0 = blockIdx.y * 32;
  const int x = threadIdx.x;
  const int y = threadIdx.y;
#pragma unroll
  for (int dy = 0; dy < 32; dy += 8)
    t[y + dy][x] = W[(size_t)(r0 + y + dy) * DL + c0 + x];
  __syncthreads();
#pragma unroll
  for (int dy = 0; dy < 32; dy += 8)
    WT[(size_t)(c0 + y + dy) * DIN + r0 + x] = (OT)t[x][y + dy];
}

// ------- fp16 MFMA encode: 256x256 tile, 8 waves, BK=64, phase-interleaved (unchanged) -----
#define BM 256
#define BN 256
#define BKE 64
#define NKT (DIN / BKE)   // 12

__global__ __launch_bounds__(512) void k_encode_f16(
    const _Float16* __restrict__ Ah, const _Float16* __restrict__ Bh,
    const float* __restrict__ b_enc, float* __restrict__ aout)
{
  __shared__ _Float16 sA[2][BM][BKE];
  __shared__ _Float16 sB[2][BN][BKE];
  const int tid = threadIdx.x, wave = tid >> 6, lane = tid & 63;
  const int wm = wave >> 2, wn = wave & 3;
  const int fr = lane & 15, fc = lane >> 4;

  const int q = ((8192 / BM) * (DL / BN)) >> 3;
  const int wg = (blockIdx.x & 7) * q + (blockIdx.x >> 3);
  const int bm = (wg / (DL / BN)) * BM;
  const int bn = (wg % (DL / BN)) * BN;

  const int lrow = lane >> 3;
  const int lcol = ((lane & 7) ^ lrow) << 3;
  const _Float16* gA = Ah + (size_t)(bm + lrow) * DIN + lcol;
  const _Float16* gB = Bh + (size_t)(bn + lrow) * DIN + lcol;

  f32x4 acc[8][4];
#pragma unroll
  for (int i = 0; i < 8; ++i)
#pragma unroll
    for (int j = 0; j < 4; ++j) acc[i][j] = f32x4{0.f, 0.f, 0.f, 0.f};

#define STAGE_TILE(buf, tt)                                                      \
  {                                                                              \
    _Pragma("unroll")                                                            \
    for (int s4 = 0; s4 < 4; ++s4) {                                             \
      const int s8 = (wave + s4 * 8) * 8;                                        \
      gl_lds16(gA + (size_t)s8 * DIN + (tt) * BKE, &sA[buf][s8][0]);             \
      gl_lds16(gB + (size_t)s8 * DIN + (tt) * BKE, &sB[buf][s8][0]);             \
    }                                                                            \
  }

#define LOADQ(p, mh, nh)                                                         \
  {                                                                              \
    const char* bA = (const char*)&sA[p][0][0];                                  \
    const char* bB = (const char*)&sB[p][0][0];                                  \
    _Pragma("unroll")                                                            \
    for (int i = 0; i < 4; ++i)                                                  \
      _Pragma("unroll")                                                          \
      for (int ks = 0; ks < 2; ++ks) {                                           \
        const int row = wm * 128 + ((mh) * 4 + i) * 16 + fr;                     \
        const int ph = (ks * 4 + fc) ^ (fr & 7);                                 \
        af[i][ks] = *(const half8*)(bA + row * (BKE * 2) + ph * 16);             \
      }                                                                          \
    _Pragma("unroll")                                                            \
    for (int j = 0; j < 2; ++j)                                                  \
      _Pragma("unroll")                                                          \
      for (int ks = 0; ks < 2; ++ks) {                                           \
        const int row = wn * 64 + ((nh) * 2 + j) * 16 + fr;                      \
        const int ph = (ks * 4 + fc) ^ (fr & 7);                                 \
        bf[j][ks] = *(const half8*)(bB + row * (BKE * 2) + ph * 16);             \
      }                                                                          \
  }

#define MFMAQ(mh, nh)                                                            \
  __builtin_amdgcn_s_setprio(1);                                                 \
  _Pragma("unroll")                                                              \
  for (int i = 0; i < 4; ++i)                                                    \
    _Pragma("unroll")                                                            \
    for (int j = 0; j < 2; ++j)                                                  \
      _Pragma("unroll")                                                          \
      for (int ks = 0; ks < 2; ++ks)                                             \
        acc[(mh) * 4 + i][(nh) * 2 + j] = __builtin_amdgcn_mfma_f32_16x16x32_f16( \
            af[i][ks], bf[j][ks], acc[(mh) * 4 + i][(nh) * 2 + j], 0, 0, 0);     \
  __builtin_amdgcn_s_setprio(0);

  half8 af[4][2], bf[2][2];

  STAGE_TILE(0, 0)
  wait_vm0();
  __builtin_amdgcn_s_barrier();

#pragma unroll 1
  for (int t = 0; t < NKT; ++t) {
    const int p = t & 1;
    LOADQ(p, 0, 0)
    if (t + 1 < NKT) STAGE_TILE(p ^ 1, t + 1)
    __builtin_amdgcn_s_barrier();
    wait_lgkm0_fence();
    MFMAQ(0, 0)
    __builtin_amdgcn_s_barrier();
    LOADQ(p, 0, 1)
    __builtin_amdgcn_s_barrier();
    wait_lgkm0_fence();
    MFMAQ(0, 1)
    __builtin_amdgcn_s_barrier();
    LOADQ(p, 1, 0)
    __builtin_amdgcn_s_barrier();
    wait_lgkm0_fence();
    MFMAQ(1, 0)
    __builtin_amdgcn_s_barrier();
    LOADQ(p, 1, 1)
    wait_vm0();
    __builtin_amdgcn_s_barrier();
    wait_lgkm0_fence();
    MFMAQ(1, 1)
    __builtin_amdgcn_s_barrier();
  }

#pragma unroll
  for (int j = 0; j < 4; ++j) {
    const int col = bn + wn * 64 + j * 16 + fr;
    const float be = b_enc[col];
#pragma unroll
    for (int i = 0; i < 8; ++i) {
      const int row0 = bm + wm * 128 + i * 16 + fc * 4;
#pragma unroll
      for (int r = 0; r < 4; ++r)
        aout[(size_t)(row0 + r) * DL + col] = acc[i][j][r] + be;
    }
  }
#undef STAGE_TILE
#undef LOADQ
#undef MFMAQ
}

// ================= FUSED back end: select + f64 recheck + z + decode, one block/row ========
__global__ __launch_bounds__(256) void k_fused(
    const float* __restrict__ a, const float* __restrict__ x,
    const float* __restrict__ b_pre, const float* __restrict__ W,
    const float* __restrict__ b_enc, const int* __restrict__ kp,
    const _Float16* __restrict__ WT, const float* __restrict__ b_dec,
    float* __restrict__ z, float* __restrict__ xhat)
{
  const int row = blockIdx.x, tid = threadIdx.x;
  const int wave = tid >> 6, lane = tid & 63;
  const int kk = min(max(kp[0], 1), KMAX);
  const float* ar = a + (size_t)row * DL;
  float* zr = z + (size_t)row * DL;

  __shared__ unsigned hist[4][512];
  __shared__ float s_wmax[4];
  __shared__ unsigned s_wsuf[4];
  __shared__ float s_Tm;
  __shared__ int s_cnt;
  __shared__ int cidx[CAP];
  __shared__ double cval[CAP];
  __shared__ double x0[DIN];
  __shared__ int widx[KMAX];
  __shared__ float wval[KMAX];

  // ---- phase 1: load a row (regs) + relu; zero z row concurrently ----
  float4 v[12];
#pragma unroll
  for (int j = 0; j < 12; ++j) {
    float4 t4 = ((const float4*)ar)[tid + 256 * j];
    t4.x = fmaxf(t4.x, 0.f); t4.y = fmaxf(t4.y, 0.f);
    t4.z = fmaxf(t4.z, 0.f); t4.w = fmaxf(t4.w, 0.f);
    v[j] = t4;
    const float4 zz = {0.f, 0.f, 0.f, 0.f};
    ((float4*)zr)[tid + 256 * j] = zz;
  }
  float m = 0.f;
#pragma unroll
  for (int j = 0; j < 12; ++j)
    m = fmaxf(m, fmaxf(fmaxf(v[j].x, v[j].y), fmaxf(v[j].z, v[j].w)));
#pragma unroll
  for (int off = 32; off; off >>= 1) m = fmaxf(m, __shfl_xor(m, off));
  if (lane == 0) s_wmax[wave] = m;
  if (tid == 0) { s_cnt = 0; s_Tm = -1.f; }
  __syncthreads();
  const float rmax = fmaxf(fmaxf(s_wmax[0], s_wmax[1]), fmaxf(s_wmax[2], s_wmax[3]));

  // ---- phase 2: adaptive 512-bin histogram threshold (2-level), wave-shfl suffix scan ----
  float Tm;
  if (rmax <= 0.f) {
    Tm = 1e30f;
  } else {
    const float scale = 512.f / rmax;
    unsigned need = (unsigned)kk;
    bool found = false;
    for (int phase = 0; phase < 2 && !found; ++phase) {
      for (int i = tid; i < 4 * 512; i += 256) (&hist[0][0])[i] = 0u;
      __syncthreads();
      unsigned* h = hist[wave];
      const float sc = (phase == 0) ? scale : scale * 8.f;
#pragma unroll
      for (int j = 0; j < 12; ++j) {
        const float vv[4] = {v[j].x, v[j].y, v[j].z, v[j].w};
#pragma unroll
        for (int e = 0; e < 4; ++e) {
          const float val = vv[e];
          if (val > 0.f) {
            const float fb = val * scale;
            if (phase == 0) {
              if (fb >= 64.f) atomicAdd(&h[min(511, (int)fb)], 1u);
            } else {
              if (fb < 64.f) atomicAdd(&h[min(511, (int)(val * sc))], 1u);
            }
          }
        }
      }
      __syncthreads();
      // pair (2*tid, 2*tid+1) totals across the 4 copies
      const unsigned lo = hist[0][2 * tid] + hist[1][2 * tid] + hist[2][2 * tid] + hist[3][2 * tid];
      const unsigned hi = hist[0][2 * tid + 1] + hist[1][2 * tid + 1] + hist[2][2 * tid + 1] + hist[3][2 * tid + 1];
      const unsigned st = lo + hi;
      // wave-internal inclusive suffix scan (descending tid = descending bins)
      unsigned s = st;
#pragma unroll
      for (int off = 1; off < 64; off <<= 1) {
        const unsigned o = __shfl_down(s, off);
        if (lane + off < 64) s += o;
      }
      if (lane == 0) s_wsuf[wave] = s;
      __syncthreads();
      unsigned above_w = 0;
#pragma unroll
      for (int w2 = 0; w2 < 4; ++w2) if (w2 > wave) above_w += s_wsuf[w2];
      const unsigned inc = s + above_w;            // suffix incl. this pair
      const unsigned excl = inc - st;              // strictly above this pair
      const unsigned total = s_wsuf[0] + s_wsuf[1] + s_wsuf[2] + s_wsuf[3];
      if (total >= need) {
        if (inc >= need && excl < need) {          // unique crossing pair
          const int bin = (excl + hi >= need) ? (2 * tid + 1) : (2 * tid);
          s_Tm = (float)bin / sc - MARGIN;
        }
        found = true;
      } else {
        need -= total;
      }
      __syncthreads();                             // hist reuse + s_Tm publish
    }
    Tm = s_Tm;                                     // -1 if < k positives
  }

  // ---- phase 3: candidate compaction into LDS ----
#pragma unroll
  for (int j = 0; j < 12; ++j) {
    const float vv[4] = {v[j].x, v[j].y, v[j].z, v[j].w};
#pragma unroll
    for (int e = 0; e < 4; ++e) {
      if (vv[e] > 0.f && vv[e] >= Tm) {
        const int p = atomicAdd(&s_cnt, 1);
        if (p < CAP) cidx[p] = (tid + 256 * j) * 4 + e;
      }
    }
  }
  // x0 load overlaps the compaction barrier
  for (int i = tid; i < DIN; i += 256)
    x0[i] = (double)x[(size_t)row * DIN + i] - (double)b_pre[i];
  __syncthreads();
  const int C = min(s_cnt, CAP);

  // ---- phase 4: exact f64 dots for candidates ----
  for (int c = wave; c < C; c += 4) {
    const int idx = cidx[c];
    const float* wrow = W + (size_t)idx * DIN;
    double s = 0.0;
#pragma unroll
    for (int it = 0; it < DIN / 64; ++it)
      s = fma(x0[lane + it * 64], (double)wrow[lane + it * 64], s);
#pragma unroll
    for (int mm = 32; mm; mm >>= 1) s += __shfl_xor(s, mm);
    if (lane == 0) cval[c] = s + (double)b_enc[idx];
  }
  __syncthreads();

  // ---- phase 5: exact ranking (ties by lowest index); winners -> widx/wval ----
  if (tid < C) {
    const int myidx = cidx[tid];
    const double vv = cval[tid];
    const double myrv = vv > 0.0 ? vv : 0.0;
    int r = 0;
    for (int j = 0; j < C; ++j) {
      const double rj = cval[j] > 0.0 ? cval[j] : 0.0;
      if (rj > myrv || (rj == myrv && cidx[j] < myidx)) ++r;
    }
    if (r < kk) { widx[r] = myidx; wval[r] = (float)myrv; }
  }
  __syncthreads();
  const int nW = min(C, kk);

  // ---- phase 6: z scatter (exact values) ----
  if (tid < nW) zr[widx[tid]] = wval[tid];

  // ---- phase 7: sparse decode from fp16 WT ----
  float acc0 = b_dec[tid], acc1 = b_dec[tid + 256], acc2 = b_dec[tid + 512];
  for (int j = 0; j < nW; ++j) {
    const float vv = wval[j];
    const _Float16* wr = WT + (size_t)widx[j] * DIN;
    acc0 = fmaf(vv, (float)wr[tid], acc0);
    acc1 = fmaf(vv, (float)wr[tid + 256], acc1);
    acc2 = fmaf(vv, (float)wr[tid + 512], acc2);
  }
  float* xr = xhat + (size_t)row * DIN;
  xr[tid]       = acc0;
  xr[tid + 256] = acc1;
  xr[tid + 512] = acc2;
}

// ================= legacy (small-ws) back end — R5 kernels, insurance only =================
template <int WRITE_Z>
__global__ __launch_bounds__(256) void k_select_cand(
    const float* __restrict__ a, const int* __restrict__ kp,
    float* __restrict__ z, float* __restrict__ xhat_slots, int* __restrict__ ccnt)
{
  const int row = blockIdx.x, tid = threadIdx.x;
  const unsigned k = (unsigned)min(max(kp[0], 1), KMAX);
  const float* ar = a + (size_t)row * DL;
  int* candidx = (int*)((char*)xhat_slots + (size_t)row * 3072 + 1024);

  __shared__ unsigned hist[4][512];
  __shared__ unsigned tot[512];
  __shared__ unsigned suf[256];
  __shared__ float s_wmax[4];
  __shared__ float s_Tm;
  __shared__ int s_cnt;

  float4 v[12];
#pragma unroll
  for (int j = 0; j < 12; ++j) {
    float4 t4 = ((const float4*)ar)[tid + 256 * j];
    t4.x = fmaxf(t4.x, 0.f); t4.y = fmaxf(t4.y, 0.f);
    t4.z = fmaxf(t4.z, 0.f); t4.w = fmaxf(t4.w, 0.f);
    v[j] = t4;
    if (WRITE_Z) {
      const float4 zz = {0.f, 0.f, 0.f, 0.f};
      ((float4*)(z + (size_t)row * DL))[tid + 256 * j] = zz;
    }
  }
  float m = 0.f;
#pragma unroll
  for (int j = 0; j < 12; ++j)
    m = fmaxf(m, fmaxf(fmaxf(v[j].x, v[j].y), fmaxf(v[j].z, v[j].w)));
#pragma unroll
  for (int off = 32; off; off >>= 1) m = fmaxf(m, __shfl_xor(m, off));
  if ((tid & 63) == 0) s_wmax[tid >> 6] = m;
  if (tid == 0) { s_cnt = 0; s_Tm = -1.f; }
  __syncthreads();
  const float rmax = fmaxf(fmaxf(s_wmax[0], s_wmax[1]), fmaxf(s_wmax[2], s_wmax[3]));

  float Tm;
  if (rmax <= 0.f) {
    Tm = 1e30f;
  } else {
    const float scale = 512.f / rmax;
    unsigned need = k;
    bool found = false;
    for (int phase = 0; phase < 2 && !found; ++phase) {
      for (int i = tid; i < 4 * 512; i += 256) (&hist[0][0])[i] = 0u;
      __syncthreads();
      unsigned* h = hist[tid >> 6];
      const float sc = (phase == 0) ? scale : scale * 8.f;
#pragma unroll
      for (int j = 0; j < 12; ++j) {
        const float vv[4] = {v[j].x, v[j].y, v[j].z, v[j].w};
#pragma unroll
        for (int e = 0; e < 4; ++e) {
          const float val = vv[e];
          if (val > 0.f) {
            const float fb = val * scale;
            if (phase == 0) {
              if (fb >= 64.f) atomicAdd(&h[min(511, (int)fb)], 1u);
            } else {
              if (fb < 64.f) atomicAdd(&h[min(511, (int)(val * sc))], 1u);
            }
          }
        }
      }
      __syncthreads();
      for (int b = tid; b < 512; b += 256)
        tot[b] = hist[0][b] + hist[1][b] + hist[2][b] + hist[3][b];
      __syncthreads();
      const unsigned st = tot[2 * tid] + tot[2 * tid + 1];
      suf[tid] = st;
      __syncthreads();
      for (int off = 1; off < 256; off <<= 1) {
        const unsigned add = (tid + off < 256) ? suf[tid + off] : 0u;
        __syncthreads();
        suf[tid] += add;
        __syncthreads();
      }
      const unsigned total = suf[0];
      if (total >= need) {
        const unsigned excl = suf[tid] - st;
        if (suf[tid] >= need && excl < need) {
          const unsigned hi = tot[2 * tid + 1];
          const int bin = (excl + hi >= need) ? (2 * tid + 1) : (2 * tid);
          s_Tm = (float)bin / sc - MARGIN;
        }
        found = true;
      } else {
        need -= total;
      }
      __syncthreads();
    }
    Tm = s_Tm;
  }

#pragma unroll
  for (int j = 0; j < 12; ++j) {
    const float vv[4] = {v[j].x, v[j].y, v[j].z, v[j].w};
#pragma unroll
    for (int e = 0; e < 4; ++e) {
      if (vv[e] > 0.f && vv[e] >= Tm) {
        const int p = atomicAdd(&s_cnt, 1);
        if (p < CAP) candidx[p] = (tid + 256 * j) * 4 + e;
      }
    }
  }
  __syncthreads();
  if (tid == 0) ccnt[row] = min(s_cnt, CAP);
}

__global__ __launch_bounds__(256) void k_recheck(
    const float* __restrict__ x, const float* __restrict__ b_pre,
    const float* __restrict__ W, const float* __restrict__ b_enc,
    const int* __restrict__ kp, float* __restrict__ xhat_slots,
    const int* __restrict__ ccnt, float* __restrict__ a,
    float* __restrict__ wT32, int* __restrict__ wNeed,
    float* __restrict__ z, int writeZ)
{
  const int row = blockIdx.x, tid = threadIdx.x;
  const int kk = min(max(kp[0], 1), KMAX);
  const int C = min(ccnt[row], CAP);
  int* slot = (int*)((char*)xhat_slots + (size_t)row * 3072);
  int* lidx = slot;
  float* lval = (float*)(slot + 128);
  const int* candidx = slot + 256;

  __shared__ double x0[DIN];
  __shared__ int cidx[CAP];
  __shared__ double cval[CAP];
  __shared__ float sT32;
  __shared__ int gcount;

  for (int i = tid; i < DIN; i += 256)
    x0[i] = (double)x[(size_t)row * DIN + i] - (double)b_pre[i];
  for (int i = tid; i < C; i += 256) cidx[i] = candidx[i];
  if (tid == 0) { sT32 = 1e30f; gcount = 0; }
  __syncthreads();

  const int wave = tid >> 6, lane = tid & 63;
  for (int c = wave; c < C; c += 4) {
    const int idx = cidx[c];
    const float* wrow = W + (size_t)idx * DIN;
    double s = 0.0;
    for (int kx = lane; kx < DIN; kx += 64)
      s = fma(x0[kx], (double)wrow[kx], s);
#pragma unroll
    for (int mm = 32; mm; mm >>= 1) s += __shfl_xor(s, mm);
    if (lane == 0) cval[c] = s + (double)b_enc[idx];
  }
  __syncthreads();

  double myrv = 0.0;
  if (tid < C) {
    const int myidx = cidx[tid];
    const double vv = cval[tid];
    myrv = vv > 0.0 ? vv : 0.0;
    int r = 0;
    for (int j = 0; j < C; ++j) {
      const double rj = cval[j] > 0.0 ? cval[j] : 0.0;
      if (rj > myrv || (rj == myrv && cidx[j] < myidx)) ++r;
    }
    a[(size_t)row * DL + myidx] = (float)vv;
    if (r < kk) {
      lidx[r] = myidx;
      lval[r] = (float)myrv;
      if (writeZ) z[(size_t)row * DL + myidx] = (float)myrv;
    }
    if (r == kk - 1) sT32 = (float)myrv;
  }
  for (int t2 = C + tid; t2 < kk; t2 += 256) { lidx[t2] = -1; lval[t2] = 0.f; }
  __syncthreads();
  if (tid < C && (float)myrv > sT32) atomicAdd(&gcount, 1);
  __syncthreads();
  if (tid == 0) { wT32[row] = sT32; wNeed[row] = kk - gcount; }
}

__global__ __launch_bounds__(192) void k_decode(
    const float* __restrict__ WT, const int* __restrict__ kp,
    const float* __restrict__ b_dec, float* __restrict__ xhat)
{
  const int row = blockIdx.x, tid = threadIdx.x;
  const int k = min(max(kp[0], 1), KMAX);
  const int* slot = (const int*)((const char*)xhat + (size_t)row * 3072);
  __shared__ int sidx[KMAX];
  __shared__ float sval[KMAX];
  if (tid < k) {
    const int idx = slot[tid];
    sidx[tid] = (idx < 0 || idx >= DL) ? 0 : idx;
    sval[tid] = (idx < 0) ? 0.f : ((const float*)(slot + 128))[tid];
  }
  __syncthreads();
  float4 acc = ((const float4*)b_dec)[tid];
  const float4* WT4 = (const float4*)WT;
  for (int j = 0; j < k; ++j) {
    const float vv = sval[j];
    const float4 w4 = WT4[(size_t)sidx[j] * (DIN / 4) + tid];
    acc.x = fmaf(vv, w4.x, acc.x);
    acc.y = fmaf(vv, w4.y, acc.y);
    acc.z = fmaf(vv, w4.z, acc.z);
    acc.w = fmaf(vv, w4.w, acc.w);
  }
  ((float4*)(xhat + (size_t)row * DIN))[tid] = acc;
}

__global__ __launch_bounds__(256) void k_zfinal(
    const float* __restrict__ a, const float* __restrict__ wT32,
    const int* __restrict__ wNeed, float* __restrict__ z)
{
  const int row = blockIdx.x, tid = threadIdx.x;
  const float T = wT32[row];
  const int need0 = wNeed[row];
  __shared__ int eq[CAP];
  __shared__ int ecnt;
  if (tid == 0) ecnt = 0;
  __syncthreads();
  const float* ar = a + (size_t)row * DL;
  float* zr = z + (size_t)row * DL;
  for (int i = tid * 4; i < DL; i += 1024) {
    const float4 vv = *(const float4*)&ar[i];
    const float r0 = fmaxf(vv.x, 0.f), r1 = fmaxf(vv.y, 0.f);
    const float r2 = fmaxf(vv.z, 0.f), r3 = fmaxf(vv.w, 0.f);
    float4 o;
    o.x = (r0 > T) ? r0 : 0.f;
    o.y = (r1 > T) ? r1 : 0.f;
    o.z = (r2 > T) ? r2 : 0.f;
    o.w = (r3 > T) ? r3 : 0.f;
    if (T > 0.f) {
      if (r0 == T) { int p = atomicAdd(&ecnt, 1); if (p < CAP) eq[p] = i; }
      if (r1 == T) { int p = atomicAdd(&ecnt, 1); if (p < CAP) eq[p] = i + 1; }
      if (r2 == T) { int p = atomicAdd(&ecnt, 1); if (p < CAP) eq[p] = i + 2; }
      if (r3 == T) { int p = atomicAdd(&ecnt, 1); if (p < CAP) eq[p] = i + 3; }
    }
    *(float4*)&zr[i] = o;
  }
  __syncthreads();
  if (tid == 0) {
    const int ne = min(ecnt, CAP);
    for (int i2 = 1; i2 < ne; ++i2) {
      const int vv = eq[i2];
      int j2 = i2 - 1;
      while (j2 >= 0 && eq[j2] > vv) { eq[j2 + 1] = eq[j2]; --j2; }
      eq[j2 + 1] = vv;
    }
    const int nd = min(need0, ne);
    for (int j = 0; j < nd; ++j) zr[eq[j]] = T;
  }
}

extern "C" void kernel_launch(void* const* d_in, const int* in_sizes, int n_in,
                              void* d_out, int out_size, void* d_ws, size_t ws_size,
                              hipStream_t stream)
{
  const float* x     = (const float*)d_in[0];
  const float* b_pre = (const float*)d_in[1];
  const float* W_enc = (const float*)d_in[2];
  const float* b_enc = (const float*)d_in[3];
  const float* W_dec = (const float*)d_in[4];
  const float* b_dec = (const float*)d_in[5];
  const int*   kp    = (const int*)d_in[6];
  const int M = in_sizes[0] / DIN;   // 8192

  float* xhat = (float*)d_out;
  float* z    = xhat + (size_t)M * DIN;
  float* a    = z + (size_t)M * DL;

  const bool bigws = ws_size >= ((size_t)192 << 20);

  if (bigws) {
    _Float16* WT16 = (_Float16*)((char*)d_ws + ((size_t)1 << 20));   // 18.9 MB
    _Float16* Ah   = (_Float16*)((char*)d_ws + ((size_t)64 << 20));  // 12.6 MB
    _Float16* Bh   = (_Float16*)((char*)d_ws + ((size_t)96 << 20));  // 18.9 MB

    k_split_x<<<M * DIN / 1024, 256, 0, stream>>>(x, b_pre, Ah);
    k_split_w<<<DL * DIN / 1024, 256, 0, stream>>>(W_enc, Bh);
    k_transpose<_Float16><<<dim3(DL / 32, DIN / 32), dim3(32, 8), 0, stream>>>(W_dec, WT16);
    k_encode_f16<<<(M / BM) * (DL / BN), 512, 0, stream>>>(Ah, Bh, b_enc, a);
    k_fused<<<M, 256, 0, stream>>>(a, x, b_pre, W_enc, b_enc, kp, WT16, b_dec, z, xhat);
  } else {
    // legacy path: scratch carved from z-region, strict producer/consumer ordering
    float* wT32  = (float*)d_ws;
    int*   wNeed = (int*)d_ws + M;
    int*   wCcnt = (int*)d_ws + 2 * M;
    float*    WT = (float*)z;                                  // 9.44M floats
    _Float16* Ah = (_Float16*)(z + (size_t)12 * 1024 * 1024);
    _Float16* Bh = (_Float16*)(z + (size_t)20 * 1024 * 1024);

    k_split_x<<<M * DIN / 1024, 256, 0, stream>>>(x, b_pre, Ah);
    k_split_w<<<DL * DIN / 1024, 256, 0, stream>>>(W_enc, Bh);
    k_transpose<float><<<dim3(DL / 32, DIN / 32), dim3(32, 8), 0, stream>>>(W_dec, WT);
    k_encode_f16<<<(M / BM) * (DL / BN), 512, 0, stream>>>(Ah, Bh, b_enc, a);
    k_select_cand<0><<<M, 256, 0, stream>>>(a, kp, z, xhat, wCcnt);
    k_recheck<<<M, 256, 0, stream>>>(x, b_pre, W_enc, b_enc, kp, xhat, wCcnt,
                                     a, wT32, wNeed, z, 0);
    k_decode<<<M, 192, 0, stream>>>(WT, kp, b_dec, xhat);
    k_zfinal<<<M, 256, 0, stream>>>(a, wT32, wNeed, z);
  }
}

// Round 7
// 732.075 us; speedup vs baseline: 6.7397x; 1.3666x over previous
//
#include <hip/hip_runtime.h>

#define DIN 768
#define DL  12288
#define CAP 320
#define MARGIN 0.03f
#define UB 0.015f
#define UMAX 64
#define KMAX 128

typedef __attribute__((ext_vector_type(8))) _Float16 half8;
typedef __attribute__((ext_vector_type(4))) _Float16 half4v;
typedef __attribute__((ext_vector_type(4))) float f32x4;

__device__ __forceinline__ void gl_lds16(const void* g, void* s) {
  __builtin_amdgcn_global_load_lds(
      (const __attribute__((address_space(1))) unsigned int*)g,
      (__attribute__((address_space(3))) unsigned int*)s, 16, 0, 0);
}
__device__ __forceinline__ void wait_lgkm0_fence() {
  asm volatile("s_waitcnt lgkmcnt(0)" ::: "memory");
  __builtin_amdgcn_sched_barrier(0);   // rule #18
}
__device__ __forceinline__ void wait_vm0() {
  asm volatile("s_waitcnt vmcnt(0)" ::: "memory");
}

// ---------------- fp16 conversions ----------------
__global__ __launch_bounds__(256) void k_split_x(const float* __restrict__ x,
    const float* __restrict__ b_pre, _Float16* __restrict__ Ah)
{
  const int i4 = blockIdx.x * 256 + threadIdx.x;
  const int col4 = (i4 % (DIN / 4)) * 4;
  const float4 xv = *(const float4*)&x[(size_t)i4 * 4];
  const float4 bp = *(const float4*)&b_pre[col4];
  half4v o;
  o.x = (_Float16)(xv.x - bp.x);
  o.y = (_Float16)(xv.y - bp.y);
  o.z = (_Float16)(xv.z - bp.z);
  o.w = (_Float16)(xv.w - bp.w);
  *(half4v*)&Ah[(size_t)i4 * 4] = o;
}

__global__ __launch_bounds__(256) void k_split_w(const float* __restrict__ W,
                                                 _Float16* __restrict__ Bh)
{
  const int i4 = blockIdx.x * 256 + threadIdx.x;
  const float4 wv = *(const float4*)&W[(size_t)i4 * 4];
  half4v o;
  o.x = (_Float16)wv.x; o.y = (_Float16)wv.y;
  o.z = (_Float16)wv.z; o.w = (_Float16)wv.w;
  *(half4v*)&Bh[(size_t)i4 * 4] = o;
}

// ---------------- transpose: W_dec (DIN x DL) -> WT (DL x DIN) fp16 ----------------
__global__ __launch_bounds__(256) void k_transpose(const float* __restrict__ W,
                                                   _Float16* __restrict__ WT)
{
  __shared__ float t[32][33];
  const int c0 = blockIdx.x * 32;
  const int r0 = blockIdx.y * 32;
  const int x = threadIdx.x;
  const int y = threadIdx.y;
#pragma unroll
  for (int dy = 0; dy < 32; dy += 8)
    t[y + dy][x] = W[(size_t)(r0 + y + dy) * DL + c0 + x];
  __syncthreads();
#pragma unroll
  for (int dy = 0; dy < 32; dy += 8)
    WT[(size_t)(c0 + y + dy) * DIN + r0 + x] = (_Float16)t[x][y + dy];
}

// ------- fp16 MFMA encode: 256x256 tile, 8 waves, BK=64, phase-interleaved (unchanged) -----
#define BM 256
#define BN 256
#define BKE 64
#define NKT (DIN / BKE)   // 12

__global__ __launch_bounds__(512) void k_encode_f16(
    const _Float16* __restrict__ Ah, const _Float16* __restrict__ Bh,
    const float* __restrict__ b_enc, float* __restrict__ aout)
{
  __shared__ _Float16 sA[2][BM][BKE];
  __shared__ _Float16 sB[2][BN][BKE];
  const int tid = threadIdx.x, wave = tid >> 6, lane = tid & 63;
  const int wm = wave >> 2, wn = wave & 3;
  const int fr = lane & 15, fc = lane >> 4;

  const int q = ((8192 / BM) * (DL / BN)) >> 3;
  const int wg = (blockIdx.x & 7) * q + (blockIdx.x >> 3);
  const int bm = (wg / (DL / BN)) * BM;
  const int bn = (wg % (DL / BN)) * BN;

  const int lrow = lane >> 3;
  const int lcol = ((lane & 7) ^ lrow) << 3;
  const _Float16* gA = Ah + (size_t)(bm + lrow) * DIN + lcol;
  const _Float16* gB = Bh + (size_t)(bn + lrow) * DIN + lcol;

  f32x4 acc[8][4];
#pragma unroll
  for (int i = 0; i < 8; ++i)
#pragma unroll
    for (int j = 0; j < 4; ++j) acc[i][j] = f32x4{0.f, 0.f, 0.f, 0.f};

#define STAGE_TILE(buf, tt)                                                      \
  {                                                                              \
    _Pragma("unroll")                                                            \
    for (int s4 = 0; s4 < 4; ++s4) {                                             \
      const int s8 = (wave + s4 * 8) * 8;                                        \
      gl_lds16(gA + (size_t)s8 * DIN + (tt) * BKE, &sA[buf][s8][0]);             \
      gl_lds16(gB + (size_t)s8 * DIN + (tt) * BKE, &sB[buf][s8][0]);             \
    }                                                                            \
  }

#define LOADQ(p, mh, nh)                                                         \
  {                                                                              \
    const char* bA = (const char*)&sA[p][0][0];                                  \
    const char* bB = (const char*)&sB[p][0][0];                                  \
    _Pragma("unroll")                                                            \
    for (int i = 0; i < 4; ++i)                                                  \
      _Pragma("unroll")                                                          \
      for (int ks = 0; ks < 2; ++ks) {                                           \
        const int row = wm * 128 + ((mh) * 4 + i) * 16 + fr;                     \
        const int ph = (ks * 4 + fc) ^ (fr & 7);                                 \
        af[i][ks] = *(const half8*)(bA + row * (BKE * 2) + ph * 16);             \
      }                                                                          \
    _Pragma("unroll")                                                            \
    for (int j = 0; j < 2; ++j)                                                  \
      _Pragma("unroll")                                                          \
      for (int ks = 0; ks < 2; ++ks) {                                           \
        const int row = wn * 64 + ((nh) * 2 + j) * 16 + fr;                      \
        const int ph = (ks * 4 + fc) ^ (fr & 7);                                 \
        bf[j][ks] = *(const half8*)(bB + row * (BKE * 2) + ph * 16);             \
      }                                                                          \
  }

#define MFMAQ(mh, nh)                                                            \
  __builtin_amdgcn_s_setprio(1);                                                 \
  _Pragma("unroll")                                                              \
  for (int i = 0; i < 4; ++i)                                                    \
    _Pragma("unroll")                                                            \
    for (int j = 0; j < 2; ++j)                                                  \
      _Pragma("unroll")                                                          \
      for (int ks = 0; ks < 2; ++ks)                                             \
        acc[(mh) * 4 + i][(nh) * 2 + j] = __builtin_amdgcn_mfma_f32_16x16x32_f16( \
            af[i][ks], bf[j][ks], acc[(mh) * 4 + i][(nh) * 2 + j], 0, 0, 0);     \
  __builtin_amdgcn_s_setprio(0);

  half8 af[4][2], bf[2][2];

  STAGE_TILE(0, 0)
  wait_vm0();
  __builtin_amdgcn_s_barrier();

#pragma unroll 1
  for (int t = 0; t < NKT; ++t) {
    const int p = t & 1;
    LOADQ(p, 0, 0)
    if (t + 1 < NKT) STAGE_TILE(p ^ 1, t + 1)
    __builtin_amdgcn_s_barrier();
    wait_lgkm0_fence();
    MFMAQ(0, 0)
    __builtin_amdgcn_s_barrier();
    LOADQ(p, 0, 1)
    __builtin_amdgcn_s_barrier();
    wait_lgkm0_fence();
    MFMAQ(0, 1)
    __builtin_amdgcn_s_barrier();
    LOADQ(p, 1, 0)
    __builtin_amdgcn_s_barrier();
    wait_lgkm0_fence();
    MFMAQ(1, 0)
    __builtin_amdgcn_s_barrier();
    LOADQ(p, 1, 1)
    wait_vm0();
    __builtin_amdgcn_s_barrier();
    wait_lgkm0_fence();
    MFMAQ(1, 1)
    __builtin_amdgcn_s_barrier();
  }

#pragma unroll
  for (int j = 0; j < 4; ++j) {
    const int col = bn + wn * 64 + j * 16 + fr;
    const float be = b_enc[col];
#pragma unroll
    for (int i = 0; i < 8; ++i) {
      const int row0 = bm + wm * 128 + i * 16 + fc * 4;
#pragma unroll
      for (int r = 0; r < 4; ++r)
        aout[(size_t)(row0 + r) * DL + col] = acc[i][j][r] + be;
    }
  }
#undef STAGE_TILE
#undef LOADQ
#undef MFMAQ
}

// ====== FUSED back end: select + micro-recheck (uncertain-band only) + z + decode =========
__global__ __launch_bounds__(256) void k_fused(
    const float* __restrict__ a, const float* __restrict__ x,
    const float* __restrict__ b_pre, const float* __restrict__ W,
    const float* __restrict__ b_enc, const int* __restrict__ kp,
    const _Float16* __restrict__ WT, const float* __restrict__ b_dec,
    float* __restrict__ z, float* __restrict__ xhat)
{
  const int row = blockIdx.x, tid = threadIdx.x;
  const int wave = tid >> 6, lane = tid & 63;
  const int kk = min(max(kp[0], 1), KMAX);
  const float* ar = a + (size_t)row * DL;
  float* zr = z + (size_t)row * DL;

  __shared__ unsigned hist[4][512];
  __shared__ float s_wmax[4];
  __shared__ unsigned s_wsuf[4];
  __shared__ float s_Tm;
  __shared__ int s_cnt;
  __shared__ int cidx[CAP];
  __shared__ float caf[CAP];
  __shared__ double x0[DIN];
  __shared__ float s_ak;
  __shared__ int s_ucnt, s_nw;
  __shared__ int uidx[UMAX];
  __shared__ double uex[UMAX];
  __shared__ int widx[KMAX];
  __shared__ float wval[KMAX];

  // ---- phase 1: load a row (regs) + relu; zero z row; row max ----
  float4 v[12];
#pragma unroll
  for (int j = 0; j < 12; ++j) {
    float4 t4 = ((const float4*)ar)[tid + 256 * j];
    t4.x = fmaxf(t4.x, 0.f); t4.y = fmaxf(t4.y, 0.f);
    t4.z = fmaxf(t4.z, 0.f); t4.w = fmaxf(t4.w, 0.f);
    v[j] = t4;
    const float4 zz = {0.f, 0.f, 0.f, 0.f};
    ((float4*)zr)[tid + 256 * j] = zz;
  }
  float m = 0.f;
#pragma unroll
  for (int j = 0; j < 12; ++j)
    m = fmaxf(m, fmaxf(fmaxf(v[j].x, v[j].y), fmaxf(v[j].z, v[j].w)));
#pragma unroll
  for (int off = 32; off; off >>= 1) m = fmaxf(m, __shfl_xor(m, off));
  if (lane == 0) s_wmax[wave] = m;
  if (tid == 0) { s_cnt = 0; s_Tm = -1.f; s_ak = -1e30f; s_ucnt = 0; s_nw = 0; }
  __syncthreads();
  const float rmax = fmaxf(fmaxf(s_wmax[0], s_wmax[1]), fmaxf(s_wmax[2], s_wmax[3]));

  // ---- phase 2: adaptive 512-bin histogram threshold (2-level) ----
  float Tm;
  if (rmax <= 0.f) {
    Tm = 1e30f;
  } else {
    const float scale = 512.f / rmax;
    unsigned need = (unsigned)kk;
    bool found = false;
    for (int phase = 0; phase < 2 && !found; ++phase) {
      for (int i = tid; i < 4 * 512; i += 256) (&hist[0][0])[i] = 0u;
      __syncthreads();
      unsigned* h = hist[wave];
      const float sc = (phase == 0) ? scale : scale * 8.f;
#pragma unroll
      for (int j = 0; j < 12; ++j) {
        const float vv[4] = {v[j].x, v[j].y, v[j].z, v[j].w};
#pragma unroll
        for (int e = 0; e < 4; ++e) {
          const float val = vv[e];
          if (val > 0.f) {
            const float fb = val * scale;
            if (phase == 0) {
              if (fb >= 64.f) atomicAdd(&h[min(511, (int)fb)], 1u);
            } else {
              if (fb < 64.f) atomicAdd(&h[min(511, (int)(val * sc))], 1u);
            }
          }
        }
      }
      __syncthreads();
      const unsigned lo = hist[0][2 * tid] + hist[1][2 * tid] + hist[2][2 * tid] + hist[3][2 * tid];
      const unsigned hi = hist[0][2 * tid + 1] + hist[1][2 * tid + 1] + hist[2][2 * tid + 1] + hist[3][2 * tid + 1];
      const unsigned st = lo + hi;
      unsigned s = st;
#pragma unroll
      for (int off = 1; off < 64; off <<= 1) {
        const unsigned o = __shfl_down(s, off);
        if (lane + off < 64) s += o;
      }
      if (lane == 0) s_wsuf[wave] = s;
      __syncthreads();
      unsigned above_w = 0;
#pragma unroll
      for (int w2 = 0; w2 < 4; ++w2) if (w2 > wave) above_w += s_wsuf[w2];
      const unsigned inc = s + above_w;
      const unsigned excl = inc - st;
      const unsigned total = s_wsuf[0] + s_wsuf[1] + s_wsuf[2] + s_wsuf[3];
      if (total >= need) {
        if (inc >= need && excl < need) {
          const int bin = (excl + hi >= need) ? (2 * tid + 1) : (2 * tid);
          s_Tm = (float)bin / sc - MARGIN;
        }
        found = true;
      } else {
        need -= total;
      }
      __syncthreads();
    }
    Tm = s_Tm;   // -1 if < k positives -> all positives are candidates
  }

  // ---- phase 3: candidate compaction (idx + approx value); x0 f64 load overlaps ----
#pragma unroll
  for (int j = 0; j < 12; ++j) {
    const float vv[4] = {v[j].x, v[j].y, v[j].z, v[j].w};
#pragma unroll
    for (int e = 0; e < 4; ++e) {
      if (vv[e] > 0.f && vv[e] >= Tm) {
        const int p = atomicAdd(&s_cnt, 1);
        if (p < CAP) { cidx[p] = (tid + 256 * j) * 4 + e; caf[p] = vv[e]; }
      }
    }
  }
  for (int i = tid; i < DIN; i += 256)
    x0[i] = (double)x[(size_t)row * DIN + i] - (double)b_pre[i];
  __syncthreads();
  const int C = min(s_cnt, CAP);

  // ---- phase 4: k-th largest APPROX value among candidates (O(C) rank/thread) ----
  if (C > kk) {          // block-uniform branch
    if (tid < C) {
      const float mv = caf[tid];
      const int mi = cidx[tid];
      int r = 0;
      for (int j = 0; j < C; ++j) {
        const float fj = caf[j];             // broadcast LDS read
        if (fj > mv || (fj == mv && cidx[j] < mi)) ++r;
      }
      if (r == kk - 1) s_ak = mv;
    }
    __syncthreads();
  }
  const float ak = s_ak;   // -1e30 if C<=kk: everything is a certain winner

  // ---- phase 5: classify certain-in vs uncertain band ----
  if (tid < C) {
    const float mv = caf[tid];
    if (C <= kk || mv > ak + UB) {
      const int p = atomicAdd(&s_nw, 1);     // certain winner: approx value is fine
      widx[p] = cidx[tid]; wval[p] = mv;
    } else if (mv >= ak - UB) {
      const int p = atomicAdd(&s_ucnt, 1);   // uncertain: needs exact dot
      if (p < UMAX) uidx[p] = cidx[tid];
    }
  }
  __syncthreads();
  const int ci = s_nw;
  const int ucnt = min(s_ucnt, UMAX);

  // ---- phase 6: exact f64 dots for the (few) uncertain candidates ----
  for (int c = wave; c < ucnt; c += 4) {
    const int idx = uidx[c];
    const float* wrow = W + (size_t)idx * DIN;
    double s = 0.0;
#pragma unroll
    for (int it = 0; it < DIN / 64; ++it)
      s = fma(x0[lane + it * 64], (double)wrow[lane + it * 64], s);
#pragma unroll
    for (int mm = 32; mm; mm >>= 1) s += __shfl_xor(s, mm);
    if (lane == 0) {
      const double e = s + (double)b_enc[idx];
      uex[c] = e > 0.0 ? e : 0.0;
    }
  }
  __syncthreads();

  // ---- phase 7: exact rank within uncertain set; take kk - ci ----
  const int utake = min(kk - ci, ucnt);
  if (tid < ucnt) {
    const double mv = uex[tid];
    const int mi = uidx[tid];
    int r = 0;
    for (int j = 0; j < ucnt; ++j) {
      const double fj = uex[j];
      if (fj > mv || (fj == mv && uidx[j] < mi)) ++r;
    }
    if (r < utake) {
      const int p = atomicAdd(&s_nw, 1);
      widx[p] = mi; wval[p] = (float)mv;
    }
  }
  __syncthreads();
  const int nW = s_nw;

  // ---- phase 8: z scatter ----
  if (tid < nW) zr[widx[tid]] = wval[tid];

  // ---- phase 9: sparse decode, coalesced half4 (8B/lane, 192 lanes) ----
  if (tid < 192) {
    float4 acc = ((const float4*)b_dec)[tid];
    for (int j = 0; j < nW; ++j) {
      const float vv = wval[j];
      const half4v w4 = *(const half4v*)(WT + (size_t)widx[j] * DIN + tid * 4);
      acc.x = fmaf(vv, (float)w4.x, acc.x);
      acc.y = fmaf(vv, (float)w4.y, acc.y);
      acc.z = fmaf(vv, (float)w4.z, acc.z);
      acc.w = fmaf(vv, (float)w4.w, acc.w);
    }
    ((float4*)(xhat + (size_t)row * DIN))[tid] = acc;
  }
}

extern "C" void kernel_launch(void* const* d_in, const int* in_sizes, int n_in,
                              void* d_out, int out_size, void* d_ws, size_t ws_size,
                              hipStream_t stream)
{
  const float* x     = (const float*)d_in[0];
  const float* b_pre = (const float*)d_in[1];
  const float* W_enc = (const float*)d_in[2];
  const float* b_enc = (const float*)d_in[3];
  const float* W_dec = (const float*)d_in[4];
  const float* b_dec = (const float*)d_in[5];
  const int*   kp    = (const int*)d_in[6];
  const int M = in_sizes[0] / DIN;   // 8192

  float* xhat = (float*)d_out;
  float* z    = xhat + (size_t)M * DIN;
  float* a    = z + (size_t)M * DL;

  const bool bigws = ws_size >= ((size_t)192 << 20);
  _Float16 *WT16, *Ah, *Bh;
  if (bigws) {   // all scratch in d_ws (measured ws ~3.3 GB)
    WT16 = (_Float16*)((char*)d_ws + ((size_t)1 << 20));    // 18.9 MB
    Ah   = (_Float16*)((char*)d_ws + ((size_t)64 << 20));   // 12.6 MB
    Bh   = (_Float16*)((char*)d_ws + ((size_t)96 << 20));   // 18.9 MB
  } else {       // fallback: z-region scratch, consumed before z written (k_fused is last)
    WT16 = (_Float16*)z;                                    // 18.9 MB at z base
    Ah   = (_Float16*)(z + (size_t)12 * 1024 * 1024);
    Bh   = (_Float16*)(z + (size_t)20 * 1024 * 1024);
  }

  k_split_x<<<M * DIN / 1024, 256, 0, stream>>>(x, b_pre, Ah);
  k_split_w<<<DL * DIN / 1024, 256, 0, stream>>>(W_enc, Bh);
  k_transpose<<<dim3(DL / 32, DIN / 32), dim3(32, 8), 0, stream>>>(W_dec, WT16);
  k_encode_f16<<<(M / BM) * (DL / BN), 512, 0, stream>>>(Ah, Bh, b_enc, a);
  k_fused<<<M, 256, 0, stream>>>(a, x, b_pre, W_enc, b_enc, kp, WT16, b_dec, z, xhat);
}

// Round 8
// 665.400 us; speedup vs baseline: 7.4150x; 1.1002x over previous
//
#include <hip/hip_runtime.h>

#define DIN 768
#define DL  12288
#define CAP 320
#define MARGIN 0.03f
#define UB 0.015f
#define UMAX 64
#define KMAX 128

typedef __attribute__((ext_vector_type(8))) _Float16 half8;
typedef __attribute__((ext_vector_type(4))) _Float16 half4v;
typedef __attribute__((ext_vector_type(4))) float f32x4;

__device__ __forceinline__ void gl_lds16(const void* g, void* s) {
  __builtin_amdgcn_global_load_lds(
      (const __attribute__((address_space(1))) unsigned int*)g,
      (__attribute__((address_space(3))) unsigned int*)s, 16, 0, 0);
}
__device__ __forceinline__ void wait_lgkm0_fence() {
  asm volatile("s_waitcnt lgkmcnt(0)" ::: "memory");
  __builtin_amdgcn_sched_barrier(0);   // rule #18
}
__device__ __forceinline__ void wait_vm0() {
  asm volatile("s_waitcnt vmcnt(0)" ::: "memory");
}

// ---------------- merged prep: split_x | split_w | transpose (block-range dispatch) -------
#define NBX (8192 * DIN / 1024)          // 6144
#define NBW (DL * DIN / 1024)            // 9216
#define NBT ((DL / 32) * (DIN / 32))     // 9216

__global__ __launch_bounds__(256) void k_prep(
    const float* __restrict__ x, const float* __restrict__ b_pre,
    const float* __restrict__ W_enc, const float* __restrict__ W_dec,
    _Float16* __restrict__ Ah, _Float16* __restrict__ Bh, _Float16* __restrict__ WT)
{
  const int b = blockIdx.x, tid = threadIdx.x;
  if (b < NBX) {
    const int i4 = b * 256 + tid;
    const int col4 = (i4 % (DIN / 4)) * 4;
    const float4 xv = *(const float4*)&x[(size_t)i4 * 4];
    const float4 bp = *(const float4*)&b_pre[col4];
    half4v o;
    o.x = (_Float16)(xv.x - bp.x);
    o.y = (_Float16)(xv.y - bp.y);
    o.z = (_Float16)(xv.z - bp.z);
    o.w = (_Float16)(xv.w - bp.w);
    *(half4v*)&Ah[(size_t)i4 * 4] = o;
  } else if (b < NBX + NBW) {
    const int i4 = (b - NBX) * 256 + tid;
    const float4 wv = *(const float4*)&W_enc[(size_t)i4 * 4];
    half4v o;
    o.x = (_Float16)wv.x; o.y = (_Float16)wv.y;
    o.z = (_Float16)wv.z; o.w = (_Float16)wv.w;
    *(half4v*)&Bh[(size_t)i4 * 4] = o;
  } else {
    const int idx = b - NBX - NBW;
    const int c0 = (idx % (DL / 32)) * 32;
    const int r0 = (idx / (DL / 32)) * 32;
    const int xx = tid & 31, yy = tid >> 5;
    __shared__ float t[32][33];
#pragma unroll
    for (int dy = 0; dy < 32; dy += 8)
      t[yy + dy][xx] = W_dec[(size_t)(r0 + yy + dy) * DL + c0 + xx];
    __syncthreads();
#pragma unroll
    for (int dy = 0; dy < 32; dy += 8)
      WT[(size_t)(c0 + yy + dy) * DIN + r0 + xx] = (_Float16)t[xx][yy + dy];
  }
}

// ------- fp16 MFMA encode: 256x256 tile, 8 waves, BK=64, phase-interleaved (unchanged) -----
#define BM 256
#define BN 256
#define BKE 64
#define NKT (DIN / BKE)   // 12

__global__ __launch_bounds__(512) void k_encode_f16(
    const _Float16* __restrict__ Ah, const _Float16* __restrict__ Bh,
    const float* __restrict__ b_enc, float* __restrict__ aout)
{
  __shared__ _Float16 sA[2][BM][BKE];
  __shared__ _Float16 sB[2][BN][BKE];
  const int tid = threadIdx.x, wave = tid >> 6, lane = tid & 63;
  const int wm = wave >> 2, wn = wave & 3;
  const int fr = lane & 15, fc = lane >> 4;

  const int q = ((8192 / BM) * (DL / BN)) >> 3;
  const int wg = (blockIdx.x & 7) * q + (blockIdx.x >> 3);
  const int bm = (wg / (DL / BN)) * BM;
  const int bn = (wg % (DL / BN)) * BN;

  const int lrow = lane >> 3;
  const int lcol = ((lane & 7) ^ lrow) << 3;
  const _Float16* gA = Ah + (size_t)(bm + lrow) * DIN + lcol;
  const _Float16* gB = Bh + (size_t)(bn + lrow) * DIN + lcol;

  f32x4 acc[8][4];
#pragma unroll
  for (int i = 0; i < 8; ++i)
#pragma unroll
    for (int j = 0; j < 4; ++j) acc[i][j] = f32x4{0.f, 0.f, 0.f, 0.f};

#define STAGE_TILE(buf, tt)                                                      \
  {                                                                              \
    _Pragma("unroll")                                                            \
    for (int s4 = 0; s4 < 4; ++s4) {                                             \
      const int s8 = (wave + s4 * 8) * 8;                                        \
      gl_lds16(gA + (size_t)s8 * DIN + (tt) * BKE, &sA[buf][s8][0]);             \
      gl_lds16(gB + (size_t)s8 * DIN + (tt) * BKE, &sB[buf][s8][0]);             \
    }                                                                            \
  }

#define LOADQ(p, mh, nh)                                                         \
  {                                                                              \
    const char* bA = (const char*)&sA[p][0][0];                                  \
    const char* bB = (const char*)&sB[p][0][0];                                  \
    _Pragma("unroll")                                                            \
    for (int i = 0; i < 4; ++i)                                                  \
      _Pragma("unroll")                                                          \
      for (int ks = 0; ks < 2; ++ks) {                                           \
        const int row = wm * 128 + ((mh) * 4 + i) * 16 + fr;                     \
        const int ph = (ks * 4 + fc) ^ (fr & 7);                                 \
        af[i][ks] = *(const half8*)(bA + row * (BKE * 2) + ph * 16);             \
      }                                                                          \
    _Pragma("unroll")                                                            \
    for (int j = 0; j < 2; ++j)                                                  \
      _Pragma("unroll")                                                          \
      for (int ks = 0; ks < 2; ++ks) {                                           \
        const int row = wn * 64 + ((nh) * 2 + j) * 16 + fr;                      \
        const int ph = (ks * 4 + fc) ^ (fr & 7);                                 \
        bf[j][ks] = *(const half8*)(bB + row * (BKE * 2) + ph * 16);             \
      }                                                                          \
  }

#define MFMAQ(mh, nh)                                                            \
  __builtin_amdgcn_s_setprio(1);                                                 \
  _Pragma("unroll")                                                              \
  for (int i = 0; i < 4; ++i)                                                    \
    _Pragma("unroll")                                                            \
    for (int j = 0; j < 2; ++j)                                                  \
      _Pragma("unroll")                                                          \
      for (int ks = 0; ks < 2; ++ks)                                             \
        acc[(mh) * 4 + i][(nh) * 2 + j] = __builtin_amdgcn_mfma_f32_16x16x32_f16( \
            af[i][ks], bf[j][ks], acc[(mh) * 4 + i][(nh) * 2 + j], 0, 0, 0);     \
  __builtin_amdgcn_s_setprio(0);

  half8 af[4][2], bf[2][2];

  STAGE_TILE(0, 0)
  wait_vm0();
  __builtin_amdgcn_s_barrier();

#pragma unroll 1
  for (int t = 0; t < NKT; ++t) {
    const int p = t & 1;
    LOADQ(p, 0, 0)
    if (t + 1 < NKT) STAGE_TILE(p ^ 1, t + 1)
    __builtin_amdgcn_s_barrier();
    wait_lgkm0_fence();
    MFMAQ(0, 0)
    __builtin_amdgcn_s_barrier();
    LOADQ(p, 0, 1)
    __builtin_amdgcn_s_barrier();
    wait_lgkm0_fence();
    MFMAQ(0, 1)
    __builtin_amdgcn_s_barrier();
    LOADQ(p, 1, 0)
    __builtin_amdgcn_s_barrier();
    wait_lgkm0_fence();
    MFMAQ(1, 0)
    __builtin_amdgcn_s_barrier();
    LOADQ(p, 1, 1)
    wait_vm0();
    __builtin_amdgcn_s_barrier();
    wait_lgkm0_fence();
    MFMAQ(1, 1)
    __builtin_amdgcn_s_barrier();
  }

#pragma unroll
  for (int j = 0; j < 4; ++j) {
    const int col = bn + wn * 64 + j * 16 + fr;
    const float be = b_enc[col];
#pragma unroll
    for (int i = 0; i < 8; ++i) {
      const int row0 = bm + wm * 128 + i * 16 + fc * 4;
#pragma unroll
      for (int r = 0; r < 4; ++r)
        aout[(size_t)(row0 + r) * DL + col] = acc[i][j][r] + be;
    }
  }
#undef STAGE_TILE
#undef LOADQ
#undef MFMAQ
}

// ====== FUSED back end (512 threads/row): select + band micro-recheck + z + decode ========
__global__ __launch_bounds__(512) void k_fused(
    const float* __restrict__ a, const float* __restrict__ x,
    const float* __restrict__ b_pre, const float* __restrict__ W,
    const float* __restrict__ b_enc, const int* __restrict__ kp,
    const _Float16* __restrict__ WT, const float* __restrict__ b_dec,
    float* __restrict__ z, float* __restrict__ xhat)
{
  const int row = blockIdx.x, tid = threadIdx.x;
  const int wave = tid >> 6, lane = tid & 63;   // 8 waves
  const int kk = min(max(kp[0], 1), KMAX);
  const float* ar = a + (size_t)row * DL;
  float* zr = z + (size_t)row * DL;

  __shared__ unsigned hist[4][512];
  __shared__ float s_wmax[8];
  __shared__ unsigned s_wsuf[8];
  __shared__ float s_Tm;
  __shared__ int s_cnt;
  __shared__ int cidx[CAP];
  __shared__ float caf[CAP];
  __shared__ double x0[DIN];
  __shared__ float s_ak;
  __shared__ int s_ucnt, s_nw;
  __shared__ int uidx[UMAX];
  __shared__ double uex[UMAX];
  __shared__ int widx[KMAX];
  __shared__ float wval[KMAX];

  // ---- phase 1: row load (6 float4/thread) + relu; zero z; row max ----
  float4 v[6];
#pragma unroll
  for (int j = 0; j < 6; ++j) {
    float4 t4 = ((const float4*)ar)[tid + 512 * j];
    t4.x = fmaxf(t4.x, 0.f); t4.y = fmaxf(t4.y, 0.f);
    t4.z = fmaxf(t4.z, 0.f); t4.w = fmaxf(t4.w, 0.f);
    v[j] = t4;
    const float4 zz = {0.f, 0.f, 0.f, 0.f};
    ((float4*)zr)[tid + 512 * j] = zz;
  }
  float m = 0.f;
#pragma unroll
  for (int j = 0; j < 6; ++j)
    m = fmaxf(m, fmaxf(fmaxf(v[j].x, v[j].y), fmaxf(v[j].z, v[j].w)));
#pragma unroll
  for (int off = 32; off; off >>= 1) m = fmaxf(m, __shfl_xor(m, off));
  if (lane == 0) s_wmax[wave] = m;
  if (tid == 0) { s_cnt = 0; s_Tm = -1.f; s_ak = -1e30f; s_ucnt = 0; s_nw = 0; }
  __syncthreads();
  float rmax = s_wmax[0];
#pragma unroll
  for (int w2 = 1; w2 < 8; ++w2) rmax = fmaxf(rmax, s_wmax[w2]);

  // ---- phase 2: adaptive 512-bin histogram threshold; bin b owned by thread b ----
  float Tm;
  if (rmax <= 0.f) {
    Tm = 1e30f;
  } else {
    const float scale = 512.f / rmax;
    unsigned need = (unsigned)kk;
    bool found = false;
    for (int phase = 0; phase < 2 && !found; ++phase) {
      for (int i = tid; i < 4 * 512; i += 512) (&hist[0][0])[i] = 0u;
      __syncthreads();
      unsigned* h = hist[wave & 3];
      const float sc = (phase == 0) ? scale : scale * 8.f;
#pragma unroll
      for (int j = 0; j < 6; ++j) {
        const float vv[4] = {v[j].x, v[j].y, v[j].z, v[j].w};
#pragma unroll
        for (int e = 0; e < 4; ++e) {
          const float val = vv[e];
          if (val > 0.f) {
            const float fb = val * scale;
            if (phase == 0) {
              if (fb >= 64.f) atomicAdd(&h[min(511, (int)fb)], 1u);
            } else {
              if (fb < 64.f) atomicAdd(&h[min(511, (int)(val * sc))], 1u);
            }
          }
        }
      }
      __syncthreads();
      const unsigned st = hist[0][tid] + hist[1][tid] + hist[2][tid] + hist[3][tid];
      // wave-internal inclusive suffix scan (bin = tid; higher tid = higher value)
      unsigned s = st;
#pragma unroll
      for (int off = 1; off < 64; off <<= 1) {
        const unsigned o = __shfl_down(s, off);
        if (lane + off < 64) s += o;
      }
      if (lane == 0) s_wsuf[wave] = s;
      __syncthreads();
      unsigned above_w = 0, total = 0;
#pragma unroll
      for (int w2 = 0; w2 < 8; ++w2) {
        total += s_wsuf[w2];
        if (w2 > wave) above_w += s_wsuf[w2];
      }
      const unsigned inc = s + above_w;     // count in bins >= tid
      const unsigned excl = inc - st;       // count in bins  > tid
      if (total >= need) {
        if (inc >= need && excl < need)     // unique crossing bin
          s_Tm = (float)tid / sc - MARGIN;
        found = true;
      } else {
        need -= total;
      }
      __syncthreads();
    }
    Tm = s_Tm;   // -1 if < k positives -> all positives are candidates
  }

  // ---- phase 3: candidate compaction; x0 f64 load overlaps ----
#pragma unroll
  for (int j = 0; j < 6; ++j) {
    const float vv[4] = {v[j].x, v[j].y, v[j].z, v[j].w};
#pragma unroll
    for (int e = 0; e < 4; ++e) {
      if (vv[e] > 0.f && vv[e] >= Tm) {
        const int p = atomicAdd(&s_cnt, 1);
        if (p < CAP) { cidx[p] = (tid + 512 * j) * 4 + e; caf[p] = vv[e]; }
      }
    }
  }
  for (int i = tid; i < DIN; i += 512)
    x0[i] = (double)x[(size_t)row * DIN + i] - (double)b_pre[i];
  __syncthreads();
  const int C = min(s_cnt, CAP);

  // ---- phase 4: k-th largest approx value among candidates ----
  if (C > kk) {
    if (tid < C) {
      const float mv = caf[tid];
      const int mi = cidx[tid];
      int r = 0;
      for (int j = 0; j < C; ++j) {
        const float fj = caf[j];
        if (fj > mv || (fj == mv && cidx[j] < mi)) ++r;
      }
      if (r == kk - 1) s_ak = mv;
    }
    __syncthreads();
  }
  const float ak = s_ak;

  // ---- phase 5: certain-in vs uncertain band ----
  if (tid < C) {
    const float mv = caf[tid];
    if (C <= kk || mv > ak + UB) {
      const int p = atomicAdd(&s_nw, 1);
      widx[p] = cidx[tid]; wval[p] = mv;
    } else if (mv >= ak - UB) {
      const int p = atomicAdd(&s_ucnt, 1);
      if (p < UMAX) uidx[p] = cidx[tid];
    }
  }
  __syncthreads();
  const int ci = s_nw;
  const int ucnt = min(s_ucnt, UMAX);

  // ---- phase 6: exact f64 dots for uncertain candidates ----
  for (int c = wave; c < ucnt; c += 8) {
    const int idx = uidx[c];
    const float* wrow = W + (size_t)idx * DIN;
    double s = 0.0;
#pragma unroll
    for (int it = 0; it < DIN / 64; ++it)
      s = fma(x0[lane + it * 64], (double)wrow[lane + it * 64], s);
#pragma unroll
    for (int mm = 32; mm; mm >>= 1) s += __shfl_xor(s, mm);
    if (lane == 0) {
      const double e = s + (double)b_enc[idx];
      uex[c] = e > 0.0 ? e : 0.0;
    }
  }
  __syncthreads();

  // ---- phase 7: exact rank within uncertain set; take kk - ci ----
  const int utake = min(kk - ci, ucnt);
  if (tid < ucnt) {
    const double mv = uex[tid];
    const int mi = uidx[tid];
    int r = 0;
    for (int j = 0; j < ucnt; ++j) {
      const double fj = uex[j];
      if (fj > mv || (fj == mv && uidx[j] < mi)) ++r;
    }
    if (r < utake) {
      const int p = atomicAdd(&s_nw, 1);
      widx[p] = mi; wval[p] = (float)mv;
    }
  }
  __syncthreads();
  const int nW = s_nw;

  // ---- phase 8: z scatter ----
  if (tid < nW) zr[widx[tid]] = wval[tid];

  // ---- phase 9: sparse decode, coalesced half4 (8B/lane, 192 lanes) ----
  if (tid < 192) {
    float4 acc = ((const float4*)b_dec)[tid];
    for (int j = 0; j < nW; ++j) {
      const float vv = wval[j];
      const half4v w4 = *(const half4v*)(WT + (size_t)widx[j] * DIN + tid * 4);
      acc.x = fmaf(vv, (float)w4.x, acc.x);
      acc.y = fmaf(vv, (float)w4.y, acc.y);
      acc.z = fmaf(vv, (float)w4.z, acc.z);
      acc.w = fmaf(vv, (float)w4.w, acc.w);
    }
    ((float4*)(xhat + (size_t)row * DIN))[tid] = acc;
  }
}

extern "C" void kernel_launch(void* const* d_in, const int* in_sizes, int n_in,
                              void* d_out, int out_size, void* d_ws, size_t ws_size,
                              hipStream_t stream)
{
  const float* x     = (const float*)d_in[0];
  const float* b_pre = (const float*)d_in[1];
  const float* W_enc = (const float*)d_in[2];
  const float* b_enc = (const float*)d_in[3];
  const float* W_dec = (const float*)d_in[4];
  const float* b_dec = (const float*)d_in[5];
  const int*   kp    = (const int*)d_in[6];
  const int M = in_sizes[0] / DIN;   // 8192

  float* xhat = (float*)d_out;
  float* z    = xhat + (size_t)M * DIN;
  float* a    = z + (size_t)M * DL;

  const bool bigws = ws_size >= ((size_t)192 << 20);
  _Float16 *WT16, *Ah, *Bh;
  if (bigws) {   // all scratch in d_ws (measured ws ~3.3 GB)
    WT16 = (_Float16*)((char*)d_ws + ((size_t)1 << 20));    // 18.9 MB
    Ah   = (_Float16*)((char*)d_ws + ((size_t)64 << 20));   // 12.6 MB
    Bh   = (_Float16*)((char*)d_ws + ((size_t)96 << 20));   // 18.9 MB
  } else {       // fallback: z-region scratch, consumed before z written (k_fused is last)
    WT16 = (_Float16*)z;
    Ah   = (_Float16*)(z + (size_t)12 * 1024 * 1024);
    Bh   = (_Float16*)(z + (size_t)20 * 1024 * 1024);
  }

  k_prep<<<NBX + NBW + NBT, 256, 0, stream>>>(x, b_pre, W_enc, W_dec, Ah, Bh, WT16);
  k_encode_f16<<<(M / BM) * (DL / BN), 512, 0, stream>>>(Ah, Bh, b_enc, a);
  k_fused<<<M, 512, 0, stream>>>(a, x, b_pre, W_enc, b_enc, kp, WT16, b_dec, z, xhat);
}